// Round 13
// baseline (401.565 us; speedup 1.0000x reference)
//
#include <hip/hip_runtime.h>
#include <hip/hip_bf16.h>

// HCNet: L=4 hyper-connection blocks, N=4, D=2048, B*T=4096 tokens.
// R13: full revert to best-known (R10) config; single change: gemm tile
// 128x64 -> 1024 blocks, 48KiB LDS -> 3 blocks/CU (was 2) for more
// inter-block wave overlap across the 2-phase barrier rendezvous.
// R12's transpose-fused row sums (serial wred in a streaming kernel) removed.

#define DD 2048
#define NN 4
#define LL 4
#define NTOK 4096
#define EPSF 1e-5f
#define STS 80  // ST row stride (floats)

typedef __attribute__((ext_vector_type(8))) short bf16x8;
typedef __attribute__((ext_vector_type(4))) float f32x4;
typedef __attribute__((ext_vector_type(2))) float f32x2;

__device__ __forceinline__ float bf2f(short u) {
  union { unsigned int i; float f; } v;
  v.i = ((unsigned int)(unsigned short)u) << 16;
  return v.f;
}
__device__ __forceinline__ short f2bf(float f) {
  __hip_bfloat16 h = __float2bfloat16(f);
  short s;
  __builtin_memcpy(&s, &h, 2);
  return s;
}
__device__ __forceinline__ float wred(float v) {
#pragma unroll
  for (int off = 32; off > 0; off >>= 1) v += __shfl_xor(v, off, 64);
  return v;
}
__device__ __forceinline__ void ld16(const void* g, void* l) {
  __builtin_amdgcn_global_load_lds(
      (const __attribute__((address_space(1))) void*)g,
      (__attribute__((address_space(3))) void*)l, 16, 0, 0);
}
__host__ __device__ constexpr int pofs(int k, int l) {
  return k == 0 ? 20 + l * 5
       : k == 1 ? 40 + (l - 1) * 5
       : k == 2 ? 55 + (l - 2) * 5
                : 65;
}

// ---------------- prep: gamma-scaled bf16 tables + beta/gamma ratio ---------
__global__ __launch_bounds__(256) void prep_pack(
    const float* __restrict__ W_m, const float* __restrict__ W_r,
    const float* __restrict__ W_b, const float* __restrict__ dyn_gamma,
    const float* __restrict__ norm_gamma, const float* __restrict__ norm_beta,
    short* __restrict__ gwm, short* __restrict__ gwr, short* __restrict__ gwb,
    float* __restrict__ rb) {
  const int i = blockIdx.x * 256 + threadIdx.x;  // over L*D = 8192
  const float g = dyn_gamma[i];
  gwm[i] = f2bf(g * W_m[i]);
  f32x4 r = *(const f32x4*)(W_r + (size_t)i * 4);
  f32x4 b = *(const f32x4*)(W_b + (size_t)i * 4);
  short ro[4], bo[4];
#pragma unroll
  for (int k = 0; k < 4; k++) { ro[k] = f2bf(g * r[k]); bo[k] = f2bf(g * b[k]); }
  *(unsigned long long*)(gwr + (size_t)i * 4) = *(unsigned long long*)ro;
  *(unsigned long long*)(gwb + (size_t)i * 4) = *(unsigned long long*)bo;
  rb[i] = norm_beta[i] / norm_gamma[i];
}

// ---------------- token-independent sums S0w[l][5], T0d[l][4] ---------------
__global__ __launch_bounds__(64) void prep_sums(
    const float* __restrict__ W_m, const float* __restrict__ W_r,
    const float* __restrict__ W_b, const float* __restrict__ dyn_gamma,
    float* __restrict__ S0w, float* __restrict__ T0d) {
  const int l = blockIdx.x;
  const int lane = threadIdx.x;
  float s[5] = {0, 0, 0, 0, 0}, t[4] = {0, 0, 0, 0};
  for (int d = lane; d < DD; d += 64) {
    const float g = dyn_gamma[l * DD + d];
    s[0] += g * W_m[l * DD + d];
    f32x4 r = *(const f32x4*)(W_r + ((size_t)l * DD + d) * 4);
    f32x4 b = *(const f32x4*)(W_b + ((size_t)l * DD + d) * 4);
#pragma unroll
    for (int m = 0; m < 4; m++) { s[1 + m] += g * r[m]; t[m] += g * b[m]; }
  }
#pragma unroll
  for (int m = 0; m < 5; m++) s[m] = wred(s[m]);
#pragma unroll
  for (int n = 0; n < 4; n++) t[n] = wred(t[n]);
  if (lane == 0) {
#pragma unroll
    for (int m = 0; m < 5; m++) S0w[l * 5 + m] = s[m];
#pragma unroll
    for (int n = 0; n < 4; n++) T0d[l * 4 + n] = t[n];
  }
}

// ------- transpose Wblk[l][d][e] (f32) -> Wt[l][e][d] = norm_g[d]*W (bf16) --
__global__ __launch_bounds__(256) void transpose_wblk(
    const float* __restrict__ W, const float* __restrict__ norm_gamma,
    short* __restrict__ Wt) {
  __shared__ float tile[64][65];
  const int blk = blockIdx.z;
  const int c0 = blockIdx.x * 64;
  const int r0 = blockIdx.y * 64;
  const float* Ws = W + (size_t)blk * DD * DD;
  short* Wd = Wt + (size_t)blk * DD * DD;
  const int tx = threadIdx.x & 63, ty = threadIdx.x >> 6;
#pragma unroll
  for (int r = 0; r < 16; r++) {
    const int row = ty + r * 4;
    tile[row][tx] = Ws[(size_t)(r0 + row) * DD + c0 + tx];
  }
  const float gsc = norm_gamma[blk * DD + r0 + tx];
  __syncthreads();
#pragma unroll
  for (int r = 0; r < 16; r++) {
    const int row = ty + r * 4;
    Wd[(size_t)(c0 + row) * DD + r0 + tx] = f2bf(tile[tx][row] * gsc);
  }
}

// ---------------- row sums of Wt': E1 = sum_d Wt', E0 = sum_d rb*Wt' + bias -
__global__ __launch_bounds__(256) void row_sums(
    const short* __restrict__ Wt, const float* __restrict__ rb,
    const float* __restrict__ bblk, float* __restrict__ E0,
    float* __restrict__ E1) {
  const int l = blockIdx.y;
  const int e = blockIdx.x * 4 + (threadIdx.x >> 6);
  const int lane = threadIdx.x & 63;
  const short* row = Wt + ((size_t)l * DD + e) * DD;
  const float* rbl = rb + l * DD;
  float s1 = 0.f, s0 = 0.f;
#pragma unroll
  for (int it = 0; it < 4; it++) {
    const int d0 = lane * 8 + it * 512;
    bf16x8 w = *(const bf16x8*)(row + d0);
    f32x4 r0 = *(const f32x4*)(rbl + d0), r1 = *(const f32x4*)(rbl + d0 + 4);
#pragma unroll
    for (int q = 0; q < 8; q++) {
      const float wq = bf2f(w[q]);
      s1 += wq;
      s0 += wq * ((q < 4) ? r0[q] : r1[q - 4]);
    }
  }
  s1 = wred(s1); s0 = wred(s0);
  if (lane == 0) {
    E1[l * DD + e] = s1;
    E0[l * DD + e] = s0 + bblk[l * DD + e];
  }
}

// ---------------- width0: x-dots + block-0 coefficients + hnorm -------------
__global__ __launch_bounds__(256) void width0_kernel(
    const float* __restrict__ x, short* __restrict__ b0,
    short* __restrict__ hout, f32x2* __restrict__ tst, float* __restrict__ Cc,
    float* __restrict__ ST, const float* __restrict__ A_m,
    const float* __restrict__ A_r, const short* __restrict__ gwm,
    const short* __restrict__ gwr, const float* __restrict__ s_a,
    const float* __restrict__ S0w) {
  const int wave = threadIdx.x >> 6;
  const int lane = threadIdx.x & 63;
  const int tok = blockIdx.x * 4 + wave;
  const float* xr = x + (size_t)tok * DD;
  short* b0t = b0 + (size_t)tok * DD;

  bf16x8 xb[4];
#pragma unroll
  for (int j = 0; j < 4; j++) {
    const int d0 = lane * 8 + j * 512;
    f32x4 a = *(const f32x4*)(xr + d0);
    f32x4 b = *(const f32x4*)(xr + d0 + 4);
    bf16x8 p;
#pragma unroll
    for (int q = 0; q < 4; q++) { p[q] = f2bf(a[q]); p[4 + q] = f2bf(b[q]); }
    xb[j] = p;
    *(bf16x8*)(b0t + d0) = p;
  }

  float o = 0.f, qq = 0.f, P0[4][5];
#pragma unroll
  for (int l = 0; l < 4; l++)
#pragma unroll
    for (int m = 0; m < 5; m++) P0[l][m] = 0.f;

#pragma unroll
  for (int j = 0; j < 4; j++) {
    const int d0 = lane * 8 + j * 512;
    bf16x8 wmv[4], wrv[4][4];
#pragma unroll
    for (int l = 0; l < 4; l++) {
      wmv[l] = *(const bf16x8*)(gwm + l * DD + d0);
#pragma unroll
      for (int p = 0; p < 4; p++)
        wrv[l][p] = *(const bf16x8*)(gwr + ((size_t)l * DD + d0 + 2 * p) * 4);
    }
#pragma unroll
    for (int q = 0; q < 8; q++) {
      const float hv = bf2f(xb[j][q]);
      o += hv; qq += hv * hv;
#pragma unroll
      for (int l = 0; l < 4; l++) {
        P0[l][0] += hv * bf2f(wmv[l][q]);
#pragma unroll
        for (int m = 0; m < 4; m++)
          P0[l][1 + m] += hv * bf2f(wrv[l][q >> 1][(q & 1) * 4 + m]);
      }
    }
  }
  o = wred(o); qq = wred(qq);
#pragma unroll
  for (int l = 0; l < 4; l++)
#pragma unroll
    for (int m = 0; m < 5; m++) P0[l][m] = wred(P0[l][m]);

  // block-0 width coefficients (all H rows = x)
  const float sa = s_a[0];
  const float mu = o * (1.f / DD);
  const float inv = rsqrtf(qq * (1.f / DD) - mu * mu + EPSF);
  const float t0 = tanhf(inv * (P0[0][0] - mu * S0w[0]));
  float tm[4];
#pragma unroll
  for (int m = 0; m < 4; m++)
    tm[m] = tanhf(inv * (P0[0][1 + m] - mu * S0w[1 + m]));
  float amSum = 0.f, arCol[4] = {0, 0, 0, 0};
#pragma unroll
  for (int n = 0; n < 4; n++) {
    amSum += A_m[n] + sa * t0;
#pragma unroll
    for (int m = 0; m < 4; m++) arCol[m] += A_r[n * 4 + m] + sa * tm[m];
  }

  if (lane == 0) {
    const float sh = amSum * o;
    const float sh2 = amSum * amSum * qq;
    const float mu2 = sh * (1.f / DD);
    const float inv2 = rsqrtf(sh2 * (1.f / DD) - mu2 * mu2 + EPSF);
    f32x2 t; t[0] = inv2; t[1] = mu2 * inv2;
    tst[tok] = t;
    float* STt = ST + (size_t)tok * STS;
    STt[0] = o;
    STt[4] = qq;  // G[0][0]
#pragma unroll
    for (int l = 0; l < 4; l++)
#pragma unroll
      for (int m = 0; m < 5; m++) STt[pofs(0, l) + m] = P0[l][m];
    float* Ct = Cc + (size_t)tok * 16;
#pragma unroll
    for (int n = 0; n < 4; n++) Ct[n * 4] = arCol[n];
  }

  short* hw = hout + (size_t)tok * DD;
#pragma unroll
  for (int j = 0; j < 4; j++) {
    const int d0 = lane * 8 + j * 512;
    bf16x8 ho;
#pragma unroll
    for (int q = 0; q < 8; q++) ho[q] = f2bf(amSum * bf2f(xb[j][q]));
    *(bf16x8*)(hw + d0) = ho;
  }
}

// ---------------- block GEMM: h2 = LN-folded(h @ Wt') -----------------------
// 128x64 tile, 1024 blocks (3/CU by 48KiB LDS), counted-vmcnt pipeline.
__global__ __launch_bounds__(512) void gemm_kernel(
    const short* __restrict__ A, const short* __restrict__ Bt,
    const f32x2* __restrict__ tst, const float* __restrict__ E0,
    const float* __restrict__ E1, short* __restrict__ C) {
  __shared__ short lA[2][128 * 64];
  __shared__ short lB[2][64 * 64];
  const int tid = threadIdx.x;
  const int lane = tid & 63;
  const int wave = tid >> 6;   // 0..7
  const int bid = blockIdx.x;
  // XCD swizzle: 1024 wgs, 8 XCDs -> each XCD a contiguous 128-wg chunk.
  const int wg = (bid & 7) * 128 + (bid >> 3);
  const int m0 = (wg & 31) * 128, n0 = (wg >> 5) * 64;
  const int wm = wave >> 1;    // 0..3: 32-row group
  const int wn = wave & 1;     // 0..1: 32-col group

  f32x4 acc[2][2] = {};

#define STAGE(buf, kt)                                                        \
  {                                                                           \
    const int k0 = (kt) * 64;                                                 \
    _Pragma("unroll") for (int c = 0; c < 2; c++) {                           \
      const int idx = c * 512 + tid;                                          \
      const int row = idx >> 3;                                               \
      const int colsw = (((idx & 7) ^ (row & 7)) * 8);                        \
      ld16(A + (size_t)(m0 + row) * DD + k0 + colsw,                          \
           (char*)&lA[buf][0] + idx * 16);                                    \
    }                                                                         \
    {                                                                         \
      const int idx = tid;                                                    \
      const int row = idx >> 3;                                               \
      const int colsw = (((idx & 7) ^ (row & 7)) * 8);                        \
      ld16(Bt + (size_t)(n0 + row) * DD + k0 + colsw,                         \
           (char*)&lB[buf][0] + idx * 16);                                    \
    }                                                                         \
  }

#define COMPUTE(cur)                                                          \
  {                                                                           \
    const char* bufA = (const char*)&lA[cur][0];                              \
    const char* bufB = (const char*)&lB[cur][0];                              \
    _Pragma("unroll") for (int kk = 0; kk < 2; ++kk) {                        \
      const int gsw = (kk * 64 + (lane >> 4) * 16) ^ ((lane & 7) << 4);       \
      bf16x8 af[2], bfr[2];                                                   \
      _Pragma("unroll") for (int m = 0; m < 2; m++) {                         \
        const int r = wm * 32 + m * 16 + (lane & 15);                         \
        af[m] = *(const bf16x8*)(bufA + r * 128 + gsw);                       \
      }                                                                       \
      _Pragma("unroll") for (int n = 0; n < 2; n++) {                         \
        const int r = wn * 32 + n * 16 + (lane & 15);                         \
        bfr[n] = *(const bf16x8*)(bufB + r * 128 + gsw);                      \
      }                                                                       \
      __builtin_amdgcn_s_setprio(1);                                          \
      _Pragma("unroll") for (int m = 0; m < 2; m++)                           \
        _Pragma("unroll") for (int n = 0; n < 2; n++)                         \
          acc[m][n] = __builtin_amdgcn_mfma_f32_16x16x32_bf16(                \
              af[m], bfr[n], acc[m][n], 0, 0, 0);                             \
      __builtin_amdgcn_s_setprio(0);                                          \
    }                                                                         \
  }

  STAGE(0, 0);
  for (int kt = 0; kt < 31; ++kt) {
    const int cur = kt & 1;
    STAGE(cur ^ 1, kt + 1);                       // 3 loads -> 6 outstanding
    asm volatile("s_waitcnt vmcnt(3)" ::: "memory");  // stage(kt) landed
    asm volatile("s_barrier" ::: "memory");
    COMPUTE(cur);
    asm volatile("s_barrier" ::: "memory");
  }
  asm volatile("s_waitcnt vmcnt(0)" ::: "memory");
  asm volatile("s_barrier" ::: "memory");
  COMPUTE(1);
#undef STAGE
#undef COMPUTE

  float e0c[2], e1c[2];
  int cols[2];
#pragma unroll
  for (int n = 0; n < 2; n++) {
    cols[n] = n0 + wn * 32 + n * 16 + (lane & 15);
    e0c[n] = E0[cols[n]];
    e1c[n] = E1[cols[n]];
  }
#pragma unroll
  for (int m = 0; m < 2; m++) {
    const int rbase = m0 + wm * 32 + m * 16 + ((lane >> 4) << 2);
#pragma unroll
    for (int j = 0; j < 4; j++) {
      const int row = rbase + j;
      const f32x2 iv = tst[row];
#pragma unroll
      for (int n = 0; n < 2; n++)
        C[(size_t)row * DD + cols[n]] =
            f2bf(iv[0] * acc[m][n][j] - iv[1] * e1c[n] + e0c[n]);
    }
  }
}

// ---------------- fused depth(I) + width(I+1) in basis form (1 wave/token) --
template <int I>
__global__ __launch_bounds__(256) void fused_dw(
    const short* __restrict__ h2s, const short* __restrict__ b0,
    short* __restrict__ hout, f32x2* __restrict__ tst, float* __restrict__ Cc,
    float* __restrict__ ST, const float* __restrict__ Bp,
    const float* __restrict__ s_b, const float* __restrict__ A_m,
    const float* __restrict__ A_r, const float* __restrict__ s_a,
    const float* __restrict__ S0w, const float* __restrict__ T0d,
    const short* __restrict__ gwm, const short* __restrict__ gwr,
    const short* __restrict__ gwb) {
  constexpr int NB = I + 1;   // width block index
  constexpr int NP = 3 - I;   // # of gw tables to dot (l = NB..3)
  const int wave = threadIdx.x >> 6;
  const int lane = threadIdx.x & 63;
  const int tok = blockIdx.x * 4 + wave;

  const short* vt = h2s + ((size_t)I * NTOK + tok) * DD;
  const short* bases[I + 1];
  bases[0] = b0 + (size_t)tok * DD;
#pragma unroll
  for (int k = 1; k <= I; k++)
    bases[k] = h2s + ((size_t)(k - 1) * NTOK + tok) * DD;

  bf16x8 h2r[4];
#pragma unroll
  for (int j = 0; j < 4; j++)
    h2r[j] = *(const bf16x8*)(vt + lane * 8 + j * 512);

  // ---- phase 1: dots on v = h2^I ----
  float o = 0.f;
  float Gr[I + 2] = {};   // Gr[k]=v.b_k (k<=I), Gr[I+1]=v.v
  float Tb[4] = {0, 0, 0, 0};
  float Pn[NP][5];
#pragma unroll
  for (int li = 0; li < NP; li++)
#pragma unroll
    for (int m = 0; m < 5; m++) Pn[li][m] = 0.f;

#pragma unroll
  for (int j = 0; j < 4; j++) {
    const int d0 = lane * 8 + j * 512;
    bf16x8 bsv[I + 1];
#pragma unroll
    for (int k = 0; k <= I; k++) bsv[k] = *(const bf16x8*)(bases[k] + d0);
    bf16x8 wbv[4];
#pragma unroll
    for (int p = 0; p < 4; p++)
      wbv[p] = *(const bf16x8*)(gwb + ((size_t)I * DD + d0 + 2 * p) * 4);
    bf16x8 wmv[NP], wrv[NP][4];
#pragma unroll
    for (int li = 0; li < NP; li++) {
      const int l = NB + li;
      wmv[li] = *(const bf16x8*)(gwm + l * DD + d0);
#pragma unroll
      for (int p = 0; p < 4; p++)
        wrv[li][p] = *(const bf16x8*)(gwr + ((size_t)l * DD + d0 + 2 * p) * 4);
    }
#pragma unroll
    for (int q = 0; q < 8; q++) {
      const float hv = bf2f(h2r[j][q]);
      o += hv;
      Gr[I + 1] += hv * hv;
#pragma unroll
      for (int k = 0; k <= I; k++) Gr[k] += hv * bf2f(bsv[k][q]);
#pragma unroll
      for (int n = 0; n < 4; n++)
        Tb[n] += hv * bf2f(wbv[q >> 1][(q & 1) * 4 + n]);
#pragma unroll
      for (int li = 0; li < NP; li++) {
        Pn[li][0] += hv * bf2f(wmv[li][q]);
#pragma unroll
        for (int m = 0; m < 4; m++)
          Pn[li][1 + m] += hv * bf2f(wrv[li][q >> 1][(q & 1) * 4 + m]);
      }
    }
  }
  o = wred(o);
#pragma unroll
  for (int k = 0; k <= I + 1; k++) Gr[k] = wred(Gr[k]);
#pragma unroll
  for (int n = 0; n < 4; n++) Tb[n] = wred(Tb[n]);
#pragma unroll
  for (int li = 0; li < NP; li++)
#pragma unroll
    for (int m = 0; m < 5; m++) Pn[li][m] = wred(Pn[li][m]);

  // ---- phase 2: coefficient algebra (wave-uniform) ----
  float* STt = ST + (size_t)tok * STS;
  float* Ct = Cc + (size_t)tok * 16;
  float ofull[I + 2], Gf[I + 2][I + 2], Pf[I + 2][5], Cp[4][I + 2];
#pragma unroll
  for (int k = 0; k <= I; k++) ofull[k] = STt[k];
  ofull[I + 1] = o;
#pragma unroll
  for (int k = 0; k <= I; k++)
#pragma unroll
    for (int j2 = 0; j2 <= I; j2++) Gf[k][j2] = STt[4 + k * 4 + j2];
#pragma unroll
  for (int k = 0; k <= I; k++) { Gf[k][I + 1] = Gr[k]; Gf[I + 1][k] = Gr[k]; }
  Gf[I + 1][I + 1] = Gr[I + 1];
#pragma unroll
  for (int k = 0; k <= I; k++)
#pragma unroll
    for (int m = 0; m < 5; m++) Pf[k][m] = STt[pofs(k, NB) + m];
#pragma unroll
  for (int m = 0; m < 5; m++) Pf[I + 1][m] = Pn[0][m];
#pragma unroll
  for (int n = 0; n < 4; n++)
#pragma unroll
    for (int k = 0; k <= I; k++) Cp[n][k] = Ct[n * 4 + k];

  // depth coefficients Bv (block I)
  {
    const float mu2 = o * (1.f / DD);
    const float inv2 = rsqrtf(Gr[I + 1] * (1.f / DD) - mu2 * mu2 + EPSF);
    const float sb = s_b[I];
#pragma unroll
    for (int n = 0; n < 4; n++)
      Cp[n][I + 1] = Bp[I * 4 + n] +
                     sb * tanhf(inv2 * (Tb[n] - mu2 * T0d[I * 4 + n]));
  }

  // width coefficients Am/Ar (block NB) from Gram-expanded stats
  const float sa = s_a[NB];
  float Am[4], Ar[4][4];
#pragma unroll
  for (int n = 0; n < 4; n++) {
    float sH = 0.f, sH2 = 0.f;
#pragma unroll
    for (int k = 0; k <= I + 1; k++) {
      sH += Cp[n][k] * ofull[k];
#pragma unroll
      for (int j2 = 0; j2 <= I + 1; j2++)
        sH2 += Cp[n][k] * Cp[n][j2] * Gf[k][j2];
    }
    const float mu = sH * (1.f / DD);
    const float inv = rsqrtf(sH2 * (1.f / DD) - mu * mu + EPSF);
    float S1[5];
#pragma unroll
    for (int m = 0; m < 5; m++) {
      S1[m] = 0.f;
#pragma unroll
      for (int k = 0; k <= I + 1; k++) S1[m] += Cp[n][k] * Pf[k][m];
    }
    Am[n] = A_m[NB * 4 + n] +
            sa * tanhf(inv * (S1[0] - mu * S0w[NB * 5 + 0]));
#pragma unroll
    for (int m = 0; m < 4; m++)
      Ar[n][m] = A_r[NB * 16 + n * 4 + m] +
                 sa * tanhf(inv * (S1[1 + m] - mu * S0w[NB * 5 + 1 + m]));
  }

  // new coefficient matrix and hnorm combo coefficients
  float Cn[4][I + 2], hc[I + 2];
#pragma unroll
  for (int k = 0; k <= I + 1; k++) {
    hc[k] = 0.f;
#pragma unroll
    for (int n = 0; n < 4; n++) hc[k] += Am[n] * Cp[n][k];
  }
#pragma unroll
  for (int mr = 0; mr < 4; mr++)
#pragma unroll
    for (int k = 0; k <= I + 1; k++) {
      float acc = 0.f;
#pragma unroll
      for (int n = 0; n < 4; n++) acc += Ar[n][mr] * Cp[n][k];
      Cn[mr][k] = acc;
    }

  if (lane == 0) {
    float sh = 0.f, sh2 = 0.f;
#pragma unroll
    for (int k = 0; k <= I + 1; k++) {
      sh += hc[k] * ofull[k];
#pragma unroll
      for (int j2 = 0; j2 <= I + 1; j2++) sh2 += hc[k] * hc[j2] * Gf[k][j2];
    }
    const float mu = sh * (1.f / DD);
    const float inv = rsqrtf(sh2 * (1.f / DD) - mu * mu + EPSF);
    f32x2 t; t[0] = inv; t[1] = mu * inv;
    tst[tok] = t;
    STt[I + 1] = o;
#pragma unroll
    for (int k = 0; k <= I + 1; k++) {
      STt[4 + (I + 1) * 4 + k] = Gf[I + 1][k];
      STt[4 + k * 4 + (I + 1)] = Gf[k][I + 1];
    }
#pragma unroll
    for (int li = 1; li < NP; li++)
#pragma unroll
      for (int m = 0; m < 5; m++) STt[pofs(I + 1, NB + li) + m] = Pn[li][m];
#pragma unroll
    for (int n = 0; n < 4; n++)
#pragma unroll
      for (int k = 0; k <= I + 1; k++) Ct[n * 4 + k] = Cn[n][k];
  }

  // ---- phase 3: hnorm = sum_k hc[k] * b_k ----
  short* hw = hout + (size_t)tok * DD;
#pragma unroll
  for (int j = 0; j < 4; j++) {
    const int d0 = lane * 8 + j * 512;
    bf16x8 bsv[I + 1];
#pragma unroll
    for (int k = 0; k <= I; k++) bsv[k] = *(const bf16x8*)(bases[k] + d0);
    bf16x8 ho;
#pragma unroll
    for (int q = 0; q < 8; q++) {
      float a = hc[I + 1] * bf2f(h2r[j][q]);
#pragma unroll
      for (int k = 0; k <= I; k++) a += hc[k] * bf2f(bsv[k][q]);
      ho[q] = f2bf(a);
    }
    *(bf16x8*)(hw + d0) = ho;
  }
}

// ---------------- final depth (block 3) + output combo ----------------------
__global__ __launch_bounds__(256) void depth_last(
    const short* __restrict__ h2s, const short* __restrict__ b0,
    float* __restrict__ out, const float* __restrict__ Cc,
    const float* __restrict__ Bp, const float* __restrict__ s_b,
    const float* __restrict__ T0d, const short* __restrict__ gwb) {
  const int wave = threadIdx.x >> 6;
  const int lane = threadIdx.x & 63;
  const int tok = blockIdx.x * 4 + wave;
  const short* vt = h2s + ((size_t)3 * NTOK + tok) * DD;

  bf16x8 h2r[4];
  float s1 = 0.f, s2 = 0.f, Tb[4] = {0, 0, 0, 0};
#pragma unroll
  for (int j = 0; j < 4; j++) {
    const int d0 = lane * 8 + j * 512;
    h2r[j] = *(const bf16x8*)(vt + d0);
    bf16x8 wbv[4];
#pragma unroll
    for (int p = 0; p < 4; p++)
      wbv[p] = *(const bf16x8*)(gwb + ((size_t)3 * DD + d0 + 2 * p) * 4);
#pragma unroll
    for (int q = 0; q < 8; q++) {
      const float hv = bf2f(h2r[j][q]);
      s1 += hv; s2 += hv * hv;
#pragma unroll
      for (int n = 0; n < 4; n++)
        Tb[n] += hv * bf2f(wbv[q >> 1][(q & 1) * 4 + n]);
    }
  }
  s1 = wred(s1); s2 = wred(s2);
#pragma unroll
  for (int n = 0; n < 4; n++) Tb[n] = wred(Tb[n]);

  const float mu = s1 * (1.f / DD);
  const float inv = rsqrtf(s2 * (1.f / DD) - mu * mu + EPSF);
  const float sb = s_b[3];
  float bsum = 0.f;
#pragma unroll
  for (int n = 0; n < 4; n++)
    bsum += Bp[12 + n] + sb * tanhf(inv * (Tb[n] - mu * T0d[12 + n]));

  const float* Ct = Cc + (size_t)tok * 16;
  float e[4];
#pragma unroll
  for (int k = 0; k < 4; k++) {
    e[k] = 0.f;
#pragma unroll
    for (int n = 0; n < 4; n++) e[k] += Ct[n * 4 + k];
  }

  const short* bases[4];
  bases[0] = b0 + (size_t)tok * DD;
#pragma unroll
  for (int k = 1; k < 4; k++)
    bases[k] = h2s + ((size_t)(k - 1) * NTOK + tok) * DD;

  float* orow = out + (size_t)tok * DD;
#pragma unroll
  for (int j = 0; j < 4; j++) {
    const int d0 = lane * 8 + j * 512;
    bf16x8 bsv[4];
#pragma unroll
    for (int k = 0; k < 4; k++) bsv[k] = *(const bf16x8*)(bases[k] + d0);
    f32x4 o0, o1;
#pragma unroll
    for (int q = 0; q < 8; q++) {
      float s = bsum * bf2f(h2r[j][q]);
#pragma unroll
      for (int k = 0; k < 4; k++) s += e[k] * bf2f(bsv[k][q]);
      if (q < 4) o0[q] = s; else o1[q - 4] = s;
    }
    *(f32x4*)(orow + d0) = o0;
    *(f32x4*)(orow + d0 + 4) = o1;
  }
}

extern "C" void kernel_launch(void* const* d_in, const int* in_sizes, int n_in,
                              void* d_out, int out_size, void* d_ws,
                              size_t ws_size, hipStream_t stream) {
  const float* x = (const float*)d_in[0];
  const float* A_m = (const float*)d_in[1];
  const float* A_r = (const float*)d_in[2];
  const float* Bp = (const float*)d_in[3];
  const float* W_m = (const float*)d_in[4];
  const float* W_r = (const float*)d_in[5];
  const float* W_b = (const float*)d_in[6];
  const float* s_a = (const float*)d_in[7];
  const float* s_b = (const float*)d_in[8];
  const float* dyn_gamma = (const float*)d_in[9];
  const float* norm_gamma = (const float*)d_in[10];
  const float* norm_beta = (const float*)d_in[11];
  const float* Wblk = (const float*)d_in[12];
  const float* bblk = (const float*)d_in[13];
  float* out = (float*)d_out;

  char* ws = (char*)d_ws;
  short* b0 = (short*)(ws);                    // 16 MiB: bf16 copy of x
  short* h2s = (short*)(ws + 16777216);        // 4 slots x 16 MiB
  short* hnorm = (short*)(ws + 83886080);      // 16 MiB
  char* aux = ws + 100663296;
  short* gwm = (short*)(aux);                  // 16 KiB
  short* gwr = (short*)(aux + 16384);          // 64 KiB
  short* gwb = (short*)(aux + 81920);          // 64 KiB
  float* rb = (float*)(aux + 147456);          // 32 KiB
  float* S0w = (float*)(aux + 180224);
  float* T0d = (float*)(aux + 181248);
  f32x2* tst = (f32x2*)(aux + 182272);         // 32 KiB
  float* E0 = (float*)(aux + 215040);          // 32 KiB
  float* E1 = (float*)(aux + 247808);          // 32 KiB
  float* Cc = (float*)(aux + 280576);          // 256 KiB: C[tok][4][4]
  float* ST = (float*)(aux + 542720);          // 1.25 MiB: stats[tok][80]
  short* Wt = (short*)d_out;  // recomputed every call, overwritten at end

  dim3 tb(256);
  prep_pack<<<32, tb, 0, stream>>>(W_m, W_r, W_b, dyn_gamma, norm_gamma,
                                   norm_beta, gwm, gwr, gwb, rb);
  prep_sums<<<4, dim3(64), 0, stream>>>(W_m, W_r, W_b, dyn_gamma, S0w, T0d);
  transpose_wblk<<<dim3(32, 32, 4), tb, 0, stream>>>(Wblk, norm_gamma, Wt);
  row_sums<<<dim3(512, 4), tb, 0, stream>>>(Wt, rb, bblk, E0, E1);
  width0_kernel<<<1024, tb, 0, stream>>>(x, b0, hnorm, tst, Cc, ST, A_m, A_r,
                                         gwm, gwr, s_a, S0w);
  for (int i = 0; i < LL; i++) {
    gemm_kernel<<<1024, dim3(512), 0, stream>>>(
        hnorm, Wt + (size_t)i * DD * DD, tst, E0 + i * DD, E1 + i * DD,
        h2s + (size_t)i * NTOK * DD);
    if (i == 0)
      fused_dw<0><<<1024, tb, 0, stream>>>(h2s, b0, hnorm, tst, Cc, ST, Bp,
                                           s_b, A_m, A_r, s_a, S0w, T0d, gwm,
                                           gwr, gwb);
    else if (i == 1)
      fused_dw<1><<<1024, tb, 0, stream>>>(h2s, b0, hnorm, tst, Cc, ST, Bp,
                                           s_b, A_m, A_r, s_a, S0w, T0d, gwm,
                                           gwr, gwb);
    else if (i == 2)
      fused_dw<2><<<1024, tb, 0, stream>>>(h2s, b0, hnorm, tst, Cc, ST, Bp,
                                           s_b, A_m, A_r, s_a, S0w, T0d, gwm,
                                           gwr, gwb);
    else
      depth_last<<<1024, tb, 0, stream>>>(h2s, b0, out, Cc, Bp, s_b, T0d, gwb);
  }
}

// Round 14
// 373.059 us; speedup vs baseline: 1.0764x; 1.0764x over previous
//
#include <hip/hip_runtime.h>
#include <hip/hip_bf16.h>

// HCNet: L=4 hyper-connection blocks, N=4, D=2048, B*T=4096 tokens.
// R14: gemm rebuilt as 3-buffer / prefetch-distance-2 / counted-vmcnt(6)
// pipeline (T3+T4 mechanism): loads stay in flight across the single
// per-tile barrier; stage issue interleaved with 4 MFMA quadrant phases.
// BM=256,BN=128,BK=64, 256 blocks (1/CU), 144KiB LDS. Non-gemm = R10 best.

#define DD 2048
#define NN 4
#define LL 4
#define NTOK 4096
#define EPSF 1e-5f
#define STS 80  // ST row stride (floats)

typedef __attribute__((ext_vector_type(8))) short bf16x8;
typedef __attribute__((ext_vector_type(4))) float f32x4;
typedef __attribute__((ext_vector_type(2))) float f32x2;

__device__ __forceinline__ float bf2f(short u) {
  union { unsigned int i; float f; } v;
  v.i = ((unsigned int)(unsigned short)u) << 16;
  return v.f;
}
__device__ __forceinline__ short f2bf(float f) {
  __hip_bfloat16 h = __float2bfloat16(f);
  short s;
  __builtin_memcpy(&s, &h, 2);
  return s;
}
__device__ __forceinline__ float wred(float v) {
#pragma unroll
  for (int off = 32; off > 0; off >>= 1) v += __shfl_xor(v, off, 64);
  return v;
}
__device__ __forceinline__ void ld16(const void* g, void* l) {
  __builtin_amdgcn_global_load_lds(
      (const __attribute__((address_space(1))) void*)g,
      (__attribute__((address_space(3))) void*)l, 16, 0, 0);
}
__host__ __device__ constexpr int pofs(int k, int l) {
  return k == 0 ? 20 + l * 5
       : k == 1 ? 40 + (l - 1) * 5
       : k == 2 ? 55 + (l - 2) * 5
                : 65;
}

// ---------------- prep: gamma-scaled bf16 tables + beta/gamma ratio ---------
__global__ __launch_bounds__(256) void prep_pack(
    const float* __restrict__ W_m, const float* __restrict__ W_r,
    const float* __restrict__ W_b, const float* __restrict__ dyn_gamma,
    const float* __restrict__ norm_gamma, const float* __restrict__ norm_beta,
    short* __restrict__ gwm, short* __restrict__ gwr, short* __restrict__ gwb,
    float* __restrict__ rb) {
  const int i = blockIdx.x * 256 + threadIdx.x;  // over L*D = 8192
  const float g = dyn_gamma[i];
  gwm[i] = f2bf(g * W_m[i]);
  f32x4 r = *(const f32x4*)(W_r + (size_t)i * 4);
  f32x4 b = *(const f32x4*)(W_b + (size_t)i * 4);
  short ro[4], bo[4];
#pragma unroll
  for (int k = 0; k < 4; k++) { ro[k] = f2bf(g * r[k]); bo[k] = f2bf(g * b[k]); }
  *(unsigned long long*)(gwr + (size_t)i * 4) = *(unsigned long long*)ro;
  *(unsigned long long*)(gwb + (size_t)i * 4) = *(unsigned long long*)bo;
  rb[i] = norm_beta[i] / norm_gamma[i];
}

// ---------------- token-independent sums S0w[l][5], T0d[l][4] ---------------
__global__ __launch_bounds__(64) void prep_sums(
    const float* __restrict__ W_m, const float* __restrict__ W_r,
    const float* __restrict__ W_b, const float* __restrict__ dyn_gamma,
    float* __restrict__ S0w, float* __restrict__ T0d) {
  const int l = blockIdx.x;
  const int lane = threadIdx.x;
  float s[5] = {0, 0, 0, 0, 0}, t[4] = {0, 0, 0, 0};
  for (int d = lane; d < DD; d += 64) {
    const float g = dyn_gamma[l * DD + d];
    s[0] += g * W_m[l * DD + d];
    f32x4 r = *(const f32x4*)(W_r + ((size_t)l * DD + d) * 4);
    f32x4 b = *(const f32x4*)(W_b + ((size_t)l * DD + d) * 4);
#pragma unroll
    for (int m = 0; m < 4; m++) { s[1 + m] += g * r[m]; t[m] += g * b[m]; }
  }
#pragma unroll
  for (int m = 0; m < 5; m++) s[m] = wred(s[m]);
#pragma unroll
  for (int n = 0; n < 4; n++) t[n] = wred(t[n]);
  if (lane == 0) {
#pragma unroll
    for (int m = 0; m < 5; m++) S0w[l * 5 + m] = s[m];
#pragma unroll
    for (int n = 0; n < 4; n++) T0d[l * 4 + n] = t[n];
  }
}

// ------- transpose Wblk[l][d][e] (f32) -> Wt[l][e][d] = norm_g[d]*W (bf16) --
__global__ __launch_bounds__(256) void transpose_wblk(
    const float* __restrict__ W, const float* __restrict__ norm_gamma,
    short* __restrict__ Wt) {
  __shared__ float tile[64][65];
  const int blk = blockIdx.z;
  const int c0 = blockIdx.x * 64;
  const int r0 = blockIdx.y * 64;
  const float* Ws = W + (size_t)blk * DD * DD;
  short* Wd = Wt + (size_t)blk * DD * DD;
  const int tx = threadIdx.x & 63, ty = threadIdx.x >> 6;
#pragma unroll
  for (int r = 0; r < 16; r++) {
    const int row = ty + r * 4;
    tile[row][tx] = Ws[(size_t)(r0 + row) * DD + c0 + tx];
  }
  const float gsc = norm_gamma[blk * DD + r0 + tx];
  __syncthreads();
#pragma unroll
  for (int r = 0; r < 16; r++) {
    const int row = ty + r * 4;
    Wd[(size_t)(c0 + row) * DD + r0 + tx] = f2bf(tile[tx][row] * gsc);
  }
}

// ---------------- row sums of Wt': E1 = sum_d Wt', E0 = sum_d rb*Wt' + bias -
__global__ __launch_bounds__(256) void row_sums(
    const short* __restrict__ Wt, const float* __restrict__ rb,
    const float* __restrict__ bblk, float* __restrict__ E0,
    float* __restrict__ E1) {
  const int l = blockIdx.y;
  const int e = blockIdx.x * 4 + (threadIdx.x >> 6);
  const int lane = threadIdx.x & 63;
  const short* row = Wt + ((size_t)l * DD + e) * DD;
  const float* rbl = rb + l * DD;
  float s1 = 0.f, s0 = 0.f;
#pragma unroll
  for (int it = 0; it < 4; it++) {
    const int d0 = lane * 8 + it * 512;
    bf16x8 w = *(const bf16x8*)(row + d0);
    f32x4 r0 = *(const f32x4*)(rbl + d0), r1 = *(const f32x4*)(rbl + d0 + 4);
#pragma unroll
    for (int q = 0; q < 8; q++) {
      const float wq = bf2f(w[q]);
      s1 += wq;
      s0 += wq * ((q < 4) ? r0[q] : r1[q - 4]);
    }
  }
  s1 = wred(s1); s0 = wred(s0);
  if (lane == 0) {
    E1[l * DD + e] = s1;
    E0[l * DD + e] = s0 + bblk[l * DD + e];
  }
}

// ---------------- width0: x-dots + block-0 coefficients + hnorm -------------
__global__ __launch_bounds__(256) void width0_kernel(
    const float* __restrict__ x, short* __restrict__ b0,
    short* __restrict__ hout, f32x2* __restrict__ tst, float* __restrict__ Cc,
    float* __restrict__ ST, const float* __restrict__ A_m,
    const float* __restrict__ A_r, const short* __restrict__ gwm,
    const short* __restrict__ gwr, const float* __restrict__ s_a,
    const float* __restrict__ S0w) {
  const int wave = threadIdx.x >> 6;
  const int lane = threadIdx.x & 63;
  const int tok = blockIdx.x * 4 + wave;
  const float* xr = x + (size_t)tok * DD;
  short* b0t = b0 + (size_t)tok * DD;

  bf16x8 xb[4];
#pragma unroll
  for (int j = 0; j < 4; j++) {
    const int d0 = lane * 8 + j * 512;
    f32x4 a = *(const f32x4*)(xr + d0);
    f32x4 b = *(const f32x4*)(xr + d0 + 4);
    bf16x8 p;
#pragma unroll
    for (int q = 0; q < 4; q++) { p[q] = f2bf(a[q]); p[4 + q] = f2bf(b[q]); }
    xb[j] = p;
    *(bf16x8*)(b0t + d0) = p;
  }

  float o = 0.f, qq = 0.f, P0[4][5];
#pragma unroll
  for (int l = 0; l < 4; l++)
#pragma unroll
    for (int m = 0; m < 5; m++) P0[l][m] = 0.f;

#pragma unroll
  for (int j = 0; j < 4; j++) {
    const int d0 = lane * 8 + j * 512;
    bf16x8 wmv[4], wrv[4][4];
#pragma unroll
    for (int l = 0; l < 4; l++) {
      wmv[l] = *(const bf16x8*)(gwm + l * DD + d0);
#pragma unroll
      for (int p = 0; p < 4; p++)
        wrv[l][p] = *(const bf16x8*)(gwr + ((size_t)l * DD + d0 + 2 * p) * 4);
    }
#pragma unroll
    for (int q = 0; q < 8; q++) {
      const float hv = bf2f(xb[j][q]);
      o += hv; qq += hv * hv;
#pragma unroll
      for (int l = 0; l < 4; l++) {
        P0[l][0] += hv * bf2f(wmv[l][q]);
#pragma unroll
        for (int m = 0; m < 4; m++)
          P0[l][1 + m] += hv * bf2f(wrv[l][q >> 1][(q & 1) * 4 + m]);
      }
    }
  }
  o = wred(o); qq = wred(qq);
#pragma unroll
  for (int l = 0; l < 4; l++)
#pragma unroll
    for (int m = 0; m < 5; m++) P0[l][m] = wred(P0[l][m]);

  // block-0 width coefficients (all H rows = x)
  const float sa = s_a[0];
  const float mu = o * (1.f / DD);
  const float inv = rsqrtf(qq * (1.f / DD) - mu * mu + EPSF);
  const float t0 = tanhf(inv * (P0[0][0] - mu * S0w[0]));
  float tm[4];
#pragma unroll
  for (int m = 0; m < 4; m++)
    tm[m] = tanhf(inv * (P0[0][1 + m] - mu * S0w[1 + m]));
  float amSum = 0.f, arCol[4] = {0, 0, 0, 0};
#pragma unroll
  for (int n = 0; n < 4; n++) {
    amSum += A_m[n] + sa * t0;
#pragma unroll
    for (int m = 0; m < 4; m++) arCol[m] += A_r[n * 4 + m] + sa * tm[m];
  }

  if (lane == 0) {
    const float sh = amSum * o;
    const float sh2 = amSum * amSum * qq;
    const float mu2 = sh * (1.f / DD);
    const float inv2 = rsqrtf(sh2 * (1.f / DD) - mu2 * mu2 + EPSF);
    f32x2 t; t[0] = inv2; t[1] = mu2 * inv2;
    tst[tok] = t;
    float* STt = ST + (size_t)tok * STS;
    STt[0] = o;
    STt[4] = qq;  // G[0][0]
#pragma unroll
    for (int l = 0; l < 4; l++)
#pragma unroll
      for (int m = 0; m < 5; m++) STt[pofs(0, l) + m] = P0[l][m];
    float* Ct = Cc + (size_t)tok * 16;
#pragma unroll
    for (int n = 0; n < 4; n++) Ct[n * 4] = arCol[n];
  }

  short* hw = hout + (size_t)tok * DD;
#pragma unroll
  for (int j = 0; j < 4; j++) {
    const int d0 = lane * 8 + j * 512;
    bf16x8 ho;
#pragma unroll
    for (int q = 0; q < 8; q++) ho[q] = f2bf(amSum * bf2f(xb[j][q]));
    *(bf16x8*)(hw + d0) = ho;
  }
}

// ---------------- block GEMM: h2 = LN-folded(h @ Wt') -----------------------
// 3-buffer LDS, prefetch distance 2, counted vmcnt(6), ONE barrier per tile.
// BM=256 BN=128 BK=64, 8 waves (2M x 4N), per-wave 128x32 (acc[8][2]).
__global__ __launch_bounds__(512) void gemm_kernel(
    const short* __restrict__ A, const short* __restrict__ Bt,
    const f32x2* __restrict__ tst, const float* __restrict__ E0,
    const float* __restrict__ E1, short* __restrict__ C) {
  __shared__ short lA[3][256 * 64];  // 96 KiB
  __shared__ short lB[3][128 * 64];  // 48 KiB
  const int tid = threadIdx.x;
  const int lane = tid & 63;
  const int wave = tid >> 6;
  const int bid = blockIdx.x;
  // XCD swizzle: 256 wgs, 8 XCDs -> contiguous 32-wg chunk per XCD.
  const int wg = (bid & 7) * 32 + (bid >> 3);
  const int m0 = (wg & 15) * 256, n0 = (wg >> 4) * 128;
  const int wm = wave >> 2;   // 0..1: 128-row half
  const int wn = wave & 3;    // 0..3: 32-col group

  f32x4 acc[8][2] = {};

  // stage part p of tile kt into buffer buf:
  //   p=0: A chunks 0,1 ; p=1: A chunks 2,3 ; p=2: B chunks 0,1
  //   (6 x ld16 per thread per tile, issued as 3 parts of 2)
#define STAGEP(buf, kt, p)                                                    \
  {                                                                           \
    const int k0 = (kt) * 64;                                                 \
    if ((p) < 2) {                                                            \
      _Pragma("unroll") for (int c = 0; c < 2; c++) {                         \
        const int idx = ((p) * 2 + c) * 512 + tid;                            \
        const int row = idx >> 3;                                             \
        const int colsw = (((idx & 7) ^ (row & 7)) * 8);                      \
        ld16(A + (size_t)(m0 + row) * DD + k0 + colsw,                        \
             (char*)&lA[buf][0] + idx * 16);                                  \
      }                                                                       \
    } else {                                                                  \
      _Pragma("unroll") for (int c = 0; c < 2; c++) {                         \
        const int idx = c * 512 + tid;                                        \
        const int row = idx >> 3;                                             \
        const int colsw = (((idx & 7) ^ (row & 7)) * 8);                      \
        ld16(Bt + (size_t)(n0 + row) * DD + k0 + colsw,                       \
             (char*)&lB[buf][0] + idx * 16);                                  \
      }                                                                       \
    }                                                                         \
  }

  // prologue: stage tiles 0 and 1 (12 loads); wait for tile 0's 6.
  STAGEP(0, 0, 0); STAGEP(0, 0, 1); STAGEP(0, 0, 2);
  STAGEP(1, 1, 0); STAGEP(1, 1, 1); STAGEP(1, 1, 2);
  asm volatile("s_waitcnt vmcnt(6)" ::: "memory");
  asm volatile("s_barrier" ::: "memory");

  int cur = 0;
  for (int t = 0; t < 32; ++t) {
    int pre = cur + 2; if (pre >= 3) pre -= 3;   // buffer of tile t+2
    const char* bufA = (const char*)&lA[cur][0];
    const char* bufB = (const char*)&lB[cur][0];
    // B fragments once per tile
    bf16x8 bfr[2][2];
#pragma unroll
    for (int kk = 0; kk < 2; kk++) {
      const int gsw = (kk * 64 + (lane >> 4) * 16) ^ ((lane & 7) << 4);
#pragma unroll
      for (int n = 0; n < 2; n++) {
        const int r = wn * 32 + n * 16 + (lane & 15);
        bfr[n][kk] = *(const bf16x8*)(bufB + r * 128 + gsw);
      }
    }
#pragma unroll
    for (int q = 0; q < 4; ++q) {
      bf16x8 af[2][2];
#pragma unroll
      for (int kk = 0; kk < 2; kk++) {
        const int gsw = (kk * 64 + (lane >> 4) * 16) ^ ((lane & 7) << 4);
#pragma unroll
        for (int mm = 0; mm < 2; mm++) {
          const int r = wm * 128 + (2 * q + mm) * 16 + (lane & 15);
          af[mm][kk] = *(const bf16x8*)(bufA + r * 128 + gsw);
        }
      }
      if (t < 30 && q < 3) STAGEP(pre, t + 2, q);
      __builtin_amdgcn_s_setprio(1);
#pragma unroll
      for (int mm = 0; mm < 2; mm++)
#pragma unroll
        for (int n = 0; n < 2; n++)
#pragma unroll
          for (int kk = 0; kk < 2; kk++)
            acc[2 * q + mm][n] = __builtin_amdgcn_mfma_f32_16x16x32_bf16(
                af[mm][kk], bfr[n][kk], acc[2 * q + mm][n], 0, 0, 0);
      __builtin_amdgcn_s_setprio(0);
    }
    if (t < 31) {
      if (t < 30)
        asm volatile("s_waitcnt vmcnt(6)" ::: "memory");  // t+1 landed
      else
        asm volatile("s_waitcnt vmcnt(0)" ::: "memory");
      asm volatile("s_barrier" ::: "memory");
    }
    cur = cur + 1; if (cur >= 3) cur = 0;
  }
#undef STAGEP

  float e0c[2], e1c[2];
  int cols[2];
#pragma unroll
  for (int n = 0; n < 2; n++) {
    cols[n] = n0 + wn * 32 + n * 16 + (lane & 15);
    e0c[n] = E0[cols[n]];
    e1c[n] = E1[cols[n]];
  }
#pragma unroll
  for (int m = 0; m < 8; m++) {
    const int rbase = m0 + wm * 128 + m * 16 + ((lane >> 4) << 2);
#pragma unroll
    for (int j = 0; j < 4; j++) {
      const int row = rbase + j;
      const f32x2 iv = tst[row];
#pragma unroll
      for (int n = 0; n < 2; n++)
        C[(size_t)row * DD + cols[n]] =
            f2bf(iv[0] * acc[m][n][j] - iv[1] * e1c[n] + e0c[n]);
    }
  }
}

// ---------------- fused depth(I) + width(I+1) in basis form (1 wave/token) --
template <int I>
__global__ __launch_bounds__(256) void fused_dw(
    const short* __restrict__ h2s, const short* __restrict__ b0,
    short* __restrict__ hout, f32x2* __restrict__ tst, float* __restrict__ Cc,
    float* __restrict__ ST, const float* __restrict__ Bp,
    const float* __restrict__ s_b, const float* __restrict__ A_m,
    const float* __restrict__ A_r, const float* __restrict__ s_a,
    const float* __restrict__ S0w, const float* __restrict__ T0d,
    const short* __restrict__ gwm, const short* __restrict__ gwr,
    const short* __restrict__ gwb) {
  constexpr int NB = I + 1;   // width block index
  constexpr int NP = 3 - I;   // # of gw tables to dot (l = NB..3)
  const int wave = threadIdx.x >> 6;
  const int lane = threadIdx.x & 63;
  const int tok = blockIdx.x * 4 + wave;

  const short* vt = h2s + ((size_t)I * NTOK + tok) * DD;
  const short* bases[I + 1];
  bases[0] = b0 + (size_t)tok * DD;
#pragma unroll
  for (int k = 1; k <= I; k++)
    bases[k] = h2s + ((size_t)(k - 1) * NTOK + tok) * DD;

  bf16x8 h2r[4];
#pragma unroll
  for (int j = 0; j < 4; j++)
    h2r[j] = *(const bf16x8*)(vt + lane * 8 + j * 512);

  // ---- phase 1: dots on v = h2^I ----
  float o = 0.f;
  float Gr[I + 2] = {};   // Gr[k]=v.b_k (k<=I), Gr[I+1]=v.v
  float Tb[4] = {0, 0, 0, 0};
  float Pn[NP][5];
#pragma unroll
  for (int li = 0; li < NP; li++)
#pragma unroll
    for (int m = 0; m < 5; m++) Pn[li][m] = 0.f;

#pragma unroll
  for (int j = 0; j < 4; j++) {
    const int d0 = lane * 8 + j * 512;
    bf16x8 bsv[I + 1];
#pragma unroll
    for (int k = 0; k <= I; k++) bsv[k] = *(const bf16x8*)(bases[k] + d0);
    bf16x8 wbv[4];
#pragma unroll
    for (int p = 0; p < 4; p++)
      wbv[p] = *(const bf16x8*)(gwb + ((size_t)I * DD + d0 + 2 * p) * 4);
    bf16x8 wmv[NP], wrv[NP][4];
#pragma unroll
    for (int li = 0; li < NP; li++) {
      const int l = NB + li;
      wmv[li] = *(const bf16x8*)(gwm + l * DD + d0);
#pragma unroll
      for (int p = 0; p < 4; p++)
        wrv[li][p] = *(const bf16x8*)(gwr + ((size_t)l * DD + d0 + 2 * p) * 4);
    }
#pragma unroll
    for (int q = 0; q < 8; q++) {
      const float hv = bf2f(h2r[j][q]);
      o += hv;
      Gr[I + 1] += hv * hv;
#pragma unroll
      for (int k = 0; k <= I; k++) Gr[k] += hv * bf2f(bsv[k][q]);
#pragma unroll
      for (int n = 0; n < 4; n++)
        Tb[n] += hv * bf2f(wbv[q >> 1][(q & 1) * 4 + n]);
#pragma unroll
      for (int li = 0; li < NP; li++) {
        Pn[li][0] += hv * bf2f(wmv[li][q]);
#pragma unroll
        for (int m = 0; m < 4; m++)
          Pn[li][1 + m] += hv * bf2f(wrv[li][q >> 1][(q & 1) * 4 + m]);
      }
    }
  }
  o = wred(o);
#pragma unroll
  for (int k = 0; k <= I + 1; k++) Gr[k] = wred(Gr[k]);
#pragma unroll
  for (int n = 0; n < 4; n++) Tb[n] = wred(Tb[n]);
#pragma unroll
  for (int li = 0; li < NP; li++)
#pragma unroll
    for (int m = 0; m < 5; m++) Pn[li][m] = wred(Pn[li][m]);

  // ---- phase 2: coefficient algebra (wave-uniform) ----
  float* STt = ST + (size_t)tok * STS;
  float* Ct = Cc + (size_t)tok * 16;
  float ofull[I + 2], Gf[I + 2][I + 2], Pf[I + 2][5], Cp[4][I + 2];
#pragma unroll
  for (int k = 0; k <= I; k++) ofull[k] = STt[k];
  ofull[I + 1] = o;
#pragma unroll
  for (int k = 0; k <= I; k++)
#pragma unroll
    for (int j2 = 0; j2 <= I; j2++) Gf[k][j2] = STt[4 + k * 4 + j2];
#pragma unroll
  for (int k = 0; k <= I; k++) { Gf[k][I + 1] = Gr[k]; Gf[I + 1][k] = Gr[k]; }
  Gf[I + 1][I + 1] = Gr[I + 1];
#pragma unroll
  for (int k = 0; k <= I; k++)
#pragma unroll
    for (int m = 0; m < 5; m++) Pf[k][m] = STt[pofs(k, NB) + m];
#pragma unroll
  for (int m = 0; m < 5; m++) Pf[I + 1][m] = Pn[0][m];
#pragma unroll
  for (int n = 0; n < 4; n++)
#pragma unroll
    for (int k = 0; k <= I; k++) Cp[n][k] = Ct[n * 4 + k];

  // depth coefficients Bv (block I)
  {
    const float mu2 = o * (1.f / DD);
    const float inv2 = rsqrtf(Gr[I + 1] * (1.f / DD) - mu2 * mu2 + EPSF);
    const float sb = s_b[I];
#pragma unroll
    for (int n = 0; n < 4; n++)
      Cp[n][I + 1] = Bp[I * 4 + n] +
                     sb * tanhf(inv2 * (Tb[n] - mu2 * T0d[I * 4 + n]));
  }

  // width coefficients Am/Ar (block NB) from Gram-expanded stats
  const float sa = s_a[NB];
  float Am[4], Ar[4][4];
#pragma unroll
  for (int n = 0; n < 4; n++) {
    float sH = 0.f, sH2 = 0.f;
#pragma unroll
    for (int k = 0; k <= I + 1; k++) {
      sH += Cp[n][k] * ofull[k];
#pragma unroll
      for (int j2 = 0; j2 <= I + 1; j2++)
        sH2 += Cp[n][k] * Cp[n][j2] * Gf[k][j2];
    }
    const float mu = sH * (1.f / DD);
    const float inv = rsqrtf(sH2 * (1.f / DD) - mu * mu + EPSF);
    float S1[5];
#pragma unroll
    for (int m = 0; m < 5; m++) {
      S1[m] = 0.f;
#pragma unroll
      for (int k = 0; k <= I + 1; k++) S1[m] += Cp[n][k] * Pf[k][m];
    }
    Am[n] = A_m[NB * 4 + n] +
            sa * tanhf(inv * (S1[0] - mu * S0w[NB * 5 + 0]));
#pragma unroll
    for (int m = 0; m < 4; m++)
      Ar[n][m] = A_r[NB * 16 + n * 4 + m] +
                 sa * tanhf(inv * (S1[1 + m] - mu * S0w[NB * 5 + 1 + m]));
  }

  // new coefficient matrix and hnorm combo coefficients
  float Cn[4][I + 2], hc[I + 2];
#pragma unroll
  for (int k = 0; k <= I + 1; k++) {
    hc[k] = 0.f;
#pragma unroll
    for (int n = 0; n < 4; n++) hc[k] += Am[n] * Cp[n][k];
  }
#pragma unroll
  for (int mr = 0; mr < 4; mr++)
#pragma unroll
    for (int k = 0; k <= I + 1; k++) {
      float acc = 0.f;
#pragma unroll
      for (int n = 0; n < 4; n++) acc += Ar[n][mr] * Cp[n][k];
      Cn[mr][k] = acc;
    }

  if (lane == 0) {
    float sh = 0.f, sh2 = 0.f;
#pragma unroll
    for (int k = 0; k <= I + 1; k++) {
      sh += hc[k] * ofull[k];
#pragma unroll
      for (int j2 = 0; j2 <= I + 1; j2++) sh2 += hc[k] * hc[j2] * Gf[k][j2];
    }
    const float mu = sh * (1.f / DD);
    const float inv = rsqrtf(sh2 * (1.f / DD) - mu * mu + EPSF);
    f32x2 t; t[0] = inv; t[1] = mu * inv;
    tst[tok] = t;
    STt[I + 1] = o;
#pragma unroll
    for (int k = 0; k <= I + 1; k++) {
      STt[4 + (I + 1) * 4 + k] = Gf[I + 1][k];
      STt[4 + k * 4 + (I + 1)] = Gf[k][I + 1];
    }
#pragma unroll
    for (int li = 1; li < NP; li++)
#pragma unroll
      for (int m = 0; m < 5; m++) STt[pofs(I + 1, NB + li) + m] = Pn[li][m];
#pragma unroll
    for (int n = 0; n < 4; n++)
#pragma unroll
      for (int k = 0; k <= I + 1; k++) Ct[n * 4 + k] = Cn[n][k];
  }

  // ---- phase 3: hnorm = sum_k hc[k] * b_k ----
  short* hw = hout + (size_t)tok * DD;
#pragma unroll
  for (int j = 0; j < 4; j++) {
    const int d0 = lane * 8 + j * 512;
    bf16x8 bsv[I + 1];
#pragma unroll
    for (int k = 0; k <= I; k++) bsv[k] = *(const bf16x8*)(bases[k] + d0);
    bf16x8 ho;
#pragma unroll
    for (int q = 0; q < 8; q++) {
      float a = hc[I + 1] * bf2f(h2r[j][q]);
#pragma unroll
      for (int k = 0; k <= I; k++) a += hc[k] * bf2f(bsv[k][q]);
      ho[q] = f2bf(a);
    }
    *(bf16x8*)(hw + d0) = ho;
  }
}

// ---------------- final depth (block 3) + output combo ----------------------
__global__ __launch_bounds__(256) void depth_last(
    const short* __restrict__ h2s, const short* __restrict__ b0,
    float* __restrict__ out, const float* __restrict__ Cc,
    const float* __restrict__ Bp, const float* __restrict__ s_b,
    const float* __restrict__ T0d, const short* __restrict__ gwb) {
  const int wave = threadIdx.x >> 6;
  const int lane = threadIdx.x & 63;
  const int tok = blockIdx.x * 4 + wave;
  const short* vt = h2s + ((size_t)3 * NTOK + tok) * DD;

  bf16x8 h2r[4];
  float s1 = 0.f, s2 = 0.f, Tb[4] = {0, 0, 0, 0};
#pragma unroll
  for (int j = 0; j < 4; j++) {
    const int d0 = lane * 8 + j * 512;
    h2r[j] = *(const bf16x8*)(vt + d0);
    bf16x8 wbv[4];
#pragma unroll
    for (int p = 0; p < 4; p++)
      wbv[p] = *(const bf16x8*)(gwb + ((size_t)3 * DD + d0 + 2 * p) * 4);
#pragma unroll
    for (int q = 0; q < 8; q++) {
      const float hv = bf2f(h2r[j][q]);
      s1 += hv; s2 += hv * hv;
#pragma unroll
      for (int n = 0; n < 4; n++)
        Tb[n] += hv * bf2f(wbv[q >> 1][(q & 1) * 4 + n]);
    }
  }
  s1 = wred(s1); s2 = wred(s2);
#pragma unroll
  for (int n = 0; n < 4; n++) Tb[n] = wred(Tb[n]);

  const float mu = s1 * (1.f / DD);
  const float inv = rsqrtf(s2 * (1.f / DD) - mu * mu + EPSF);
  const float sb = s_b[3];
  float bsum = 0.f;
#pragma unroll
  for (int n = 0; n < 4; n++)
    bsum += Bp[12 + n] + sb * tanhf(inv * (Tb[n] - mu * T0d[12 + n]));

  const float* Ct = Cc + (size_t)tok * 16;
  float e[4];
#pragma unroll
  for (int k = 0; k < 4; k++) {
    e[k] = 0.f;
#pragma unroll
    for (int n = 0; n < 4; n++) e[k] += Ct[n * 4 + k];
  }

  const short* bases[4];
  bases[0] = b0 + (size_t)tok * DD;
#pragma unroll
  for (int k = 1; k < 4; k++)
    bases[k] = h2s + ((size_t)(k - 1) * NTOK + tok) * DD;

  float* orow = out + (size_t)tok * DD;
#pragma unroll
  for (int j = 0; j < 4; j++) {
    const int d0 = lane * 8 + j * 512;
    bf16x8 bsv[4];
#pragma unroll
    for (int k = 0; k < 4; k++) bsv[k] = *(const bf16x8*)(bases[k] + d0);
    f32x4 o0, o1;
#pragma unroll
    for (int q = 0; q < 8; q++) {
      float s = bsum * bf2f(h2r[j][q]);
#pragma unroll
      for (int k = 0; k < 4; k++) s += e[k] * bf2f(bsv[k][q]);
      if (q < 4) o0[q] = s; else o1[q - 4] = s;
    }
    *(f32x4*)(orow + d0) = o0;
    *(f32x4*)(orow + d0 + 4) = o1;
  }
}

extern "C" void kernel_launch(void* const* d_in, const int* in_sizes, int n_in,
                              void* d_out, int out_size, void* d_ws,
                              size_t ws_size, hipStream_t stream) {
  const float* x = (const float*)d_in[0];
  const float* A_m = (const float*)d_in[1];
  const float* A_r = (const float*)d_in[2];
  const float* Bp = (const float*)d_in[3];
  const float* W_m = (const float*)d_in[4];
  const float* W_r = (const float*)d_in[5];
  const float* W_b = (const float*)d_in[6];
  const float* s_a = (const float*)d_in[7];
  const float* s_b = (const float*)d_in[8];
  const float* dyn_gamma = (const float*)d_in[9];
  const float* norm_gamma = (const float*)d_in[10];
  const float* norm_beta = (const float*)d_in[11];
  const float* Wblk = (const float*)d_in[12];
  const float* bblk = (const float*)d_in[13];
  float* out = (float*)d_out;

  char* ws = (char*)d_ws;
  short* b0 = (short*)(ws);                    // 16 MiB: bf16 copy of x
  short* h2s = (short*)(ws + 16777216);        // 4 slots x 16 MiB
  short* hnorm = (short*)(ws + 83886080);      // 16 MiB
  char* aux = ws + 100663296;
  short* gwm = (short*)(aux);                  // 16 KiB
  short* gwr = (short*)(aux + 16384);          // 64 KiB
  short* gwb = (short*)(aux + 81920);          // 64 KiB
  float* rb = (float*)(aux + 147456);          // 32 KiB
  float* S0w = (float*)(aux + 180224);
  float* T0d = (float*)(aux + 181248);
  f32x2* tst = (f32x2*)(aux + 182272);         // 32 KiB
  float* E0 = (float*)(aux + 215040);          // 32 KiB
  float* E1 = (float*)(aux + 247808);          // 32 KiB
  float* Cc = (float*)(aux + 280576);          // 256 KiB: C[tok][4][4]
  float* ST = (float*)(aux + 542720);          // 1.25 MiB: stats[tok][80]
  short* Wt = (short*)d_out;  // recomputed every call, overwritten at end

  dim3 tb(256);
  prep_pack<<<32, tb, 0, stream>>>(W_m, W_r, W_b, dyn_gamma, norm_gamma,
                                   norm_beta, gwm, gwr, gwb, rb);
  prep_sums<<<4, dim3(64), 0, stream>>>(W_m, W_r, W_b, dyn_gamma, S0w, T0d);
  transpose_wblk<<<dim3(32, 32, 4), tb, 0, stream>>>(Wblk, norm_gamma, Wt);
  row_sums<<<dim3(512, 4), tb, 0, stream>>>(Wt, rb, bblk, E0, E1);
  width0_kernel<<<1024, tb, 0, stream>>>(x, b0, hnorm, tst, Cc, ST, A_m, A_r,
                                         gwm, gwr, s_a, S0w);
  for (int i = 0; i < LL; i++) {
    gemm_kernel<<<256, dim3(512), 0, stream>>>(
        hnorm, Wt + (size_t)i * DD * DD, tst, E0 + i * DD, E1 + i * DD,
        h2s + (size_t)i * NTOK * DD);
    if (i == 0)
      fused_dw<0><<<1024, tb, 0, stream>>>(h2s, b0, hnorm, tst, Cc, ST, Bp,
                                           s_b, A_m, A_r, s_a, S0w, T0d, gwm,
                                           gwr, gwb);
    else if (i == 1)
      fused_dw<1><<<1024, tb, 0, stream>>>(h2s, b0, hnorm, tst, Cc, ST, Bp,
                                           s_b, A_m, A_r, s_a, S0w, T0d, gwm,
                                           gwr, gwb);
    else if (i == 2)
      fused_dw<2><<<1024, tb, 0, stream>>>(h2s, b0, hnorm, tst, Cc, ST, Bp,
                                           s_b, A_m, A_r, s_a, S0w, T0d, gwm,
                                           gwr, gwb);
    else
      depth_last<<<1024, tb, 0, stream>>>(h2s, b0, out, Cc, Bp, s_b, T0d, gwb);
  }
}

// Round 15
// 324.964 us; speedup vs baseline: 1.2357x; 1.1480x over previous
//
#include <hip/hip_runtime.h>
#include <hip/hip_bf16.h>

// HCNet: L=4 hyper-connection blocks, N=4, D=2048, B*T=4096 tokens.
// R15: exact restore of the best-known configuration (R10, 326.6us):
// - gemm: 128x128 tile, 512thr/8wave, XOR-swizzled LDS, counted-vmcnt(4)
//   2-phase pipeline, XCD-swizzled grid. (5-variant bracket: this is best.)
// - fused_dw: R9 basis form, 1 wave/token.
// - separate transpose + row_sums (R12's fused atomics/wred regressed).

#define DD 2048
#define NN 4
#define LL 4
#define NTOK 4096
#define EPSF 1e-5f
#define STS 80  // ST row stride (floats)

typedef __attribute__((ext_vector_type(8))) short bf16x8;
typedef __attribute__((ext_vector_type(4))) float f32x4;
typedef __attribute__((ext_vector_type(2))) float f32x2;

__device__ __forceinline__ float bf2f(short u) {
  union { unsigned int i; float f; } v;
  v.i = ((unsigned int)(unsigned short)u) << 16;
  return v.f;
}
__device__ __forceinline__ short f2bf(float f) {
  __hip_bfloat16 h = __float2bfloat16(f);
  short s;
  __builtin_memcpy(&s, &h, 2);
  return s;
}
__device__ __forceinline__ float wred(float v) {
#pragma unroll
  for (int off = 32; off > 0; off >>= 1) v += __shfl_xor(v, off, 64);
  return v;
}
__device__ __forceinline__ void ld16(const void* g, void* l) {
  __builtin_amdgcn_global_load_lds(
      (const __attribute__((address_space(1))) void*)g,
      (__attribute__((address_space(3))) void*)l, 16, 0, 0);
}
__host__ __device__ constexpr int pofs(int k, int l) {
  return k == 0 ? 20 + l * 5
       : k == 1 ? 40 + (l - 1) * 5
       : k == 2 ? 55 + (l - 2) * 5
                : 65;
}

// ---------------- prep: gamma-scaled bf16 tables + beta/gamma ratio ---------
__global__ __launch_bounds__(256) void prep_pack(
    const float* __restrict__ W_m, const float* __restrict__ W_r,
    const float* __restrict__ W_b, const float* __restrict__ dyn_gamma,
    const float* __restrict__ norm_gamma, const float* __restrict__ norm_beta,
    short* __restrict__ gwm, short* __restrict__ gwr, short* __restrict__ gwb,
    float* __restrict__ rb) {
  const int i = blockIdx.x * 256 + threadIdx.x;  // over L*D = 8192
  const float g = dyn_gamma[i];
  gwm[i] = f2bf(g * W_m[i]);
  f32x4 r = *(const f32x4*)(W_r + (size_t)i * 4);
  f32x4 b = *(const f32x4*)(W_b + (size_t)i * 4);
  short ro[4], bo[4];
#pragma unroll
  for (int k = 0; k < 4; k++) { ro[k] = f2bf(g * r[k]); bo[k] = f2bf(g * b[k]); }
  *(unsigned long long*)(gwr + (size_t)i * 4) = *(unsigned long long*)ro;
  *(unsigned long long*)(gwb + (size_t)i * 4) = *(unsigned long long*)bo;
  rb[i] = norm_beta[i] / norm_gamma[i];
}

// ---------------- token-independent sums S0w[l][5], T0d[l][4] ---------------
__global__ __launch_bounds__(64) void prep_sums(
    const float* __restrict__ W_m, const float* __restrict__ W_r,
    const float* __restrict__ W_b, const float* __restrict__ dyn_gamma,
    float* __restrict__ S0w, float* __restrict__ T0d) {
  const int l = blockIdx.x;
  const int lane = threadIdx.x;
  float s[5] = {0, 0, 0, 0, 0}, t[4] = {0, 0, 0, 0};
  for (int d = lane; d < DD; d += 64) {
    const float g = dyn_gamma[l * DD + d];
    s[0] += g * W_m[l * DD + d];
    f32x4 r = *(const f32x4*)(W_r + ((size_t)l * DD + d) * 4);
    f32x4 b = *(const f32x4*)(W_b + ((size_t)l * DD + d) * 4);
#pragma unroll
    for (int m = 0; m < 4; m++) { s[1 + m] += g * r[m]; t[m] += g * b[m]; }
  }
#pragma unroll
  for (int m = 0; m < 5; m++) s[m] = wred(s[m]);
#pragma unroll
  for (int n = 0; n < 4; n++) t[n] = wred(t[n]);
  if (lane == 0) {
#pragma unroll
    for (int m = 0; m < 5; m++) S0w[l * 5 + m] = s[m];
#pragma unroll
    for (int n = 0; n < 4; n++) T0d[l * 4 + n] = t[n];
  }
}

// ------- transpose Wblk[l][d][e] (f32) -> Wt[l][e][d] = norm_g[d]*W (bf16) --
__global__ __launch_bounds__(256) void transpose_wblk(
    const float* __restrict__ W, const float* __restrict__ norm_gamma,
    short* __restrict__ Wt) {
  __shared__ float tile[64][65];
  const int blk = blockIdx.z;
  const int c0 = blockIdx.x * 64;
  const int r0 = blockIdx.y * 64;
  const float* Ws = W + (size_t)blk * DD * DD;
  short* Wd = Wt + (size_t)blk * DD * DD;
  const int tx = threadIdx.x & 63, ty = threadIdx.x >> 6;
#pragma unroll
  for (int r = 0; r < 16; r++) {
    const int row = ty + r * 4;
    tile[row][tx] = Ws[(size_t)(r0 + row) * DD + c0 + tx];
  }
  const float gsc = norm_gamma[blk * DD + r0 + tx];
  __syncthreads();
#pragma unroll
  for (int r = 0; r < 16; r++) {
    const int row = ty + r * 4;
    Wd[(size_t)(c0 + row) * DD + r0 + tx] = f2bf(tile[tx][row] * gsc);
  }
}

// ---------------- row sums of Wt': E1 = sum_d Wt', E0 = sum_d rb*Wt' + bias -
__global__ __launch_bounds__(256) void row_sums(
    const short* __restrict__ Wt, const float* __restrict__ rb,
    const float* __restrict__ bblk, float* __restrict__ E0,
    float* __restrict__ E1) {
  const int l = blockIdx.y;
  const int e = blockIdx.x * 4 + (threadIdx.x >> 6);
  const int lane = threadIdx.x & 63;
  const short* row = Wt + ((size_t)l * DD + e) * DD;
  const float* rbl = rb + l * DD;
  float s1 = 0.f, s0 = 0.f;
#pragma unroll
  for (int it = 0; it < 4; it++) {
    const int d0 = lane * 8 + it * 512;
    bf16x8 w = *(const bf16x8*)(row + d0);
    f32x4 r0 = *(const f32x4*)(rbl + d0), r1 = *(const f32x4*)(rbl + d0 + 4);
#pragma unroll
    for (int q = 0; q < 8; q++) {
      const float wq = bf2f(w[q]);
      s1 += wq;
      s0 += wq * ((q < 4) ? r0[q] : r1[q - 4]);
    }
  }
  s1 = wred(s1); s0 = wred(s0);
  if (lane == 0) {
    E1[l * DD + e] = s1;
    E0[l * DD + e] = s0 + bblk[l * DD + e];
  }
}

// ---------------- width0: x-dots + block-0 coefficients + hnorm -------------
__global__ __launch_bounds__(256) void width0_kernel(
    const float* __restrict__ x, short* __restrict__ b0,
    short* __restrict__ hout, f32x2* __restrict__ tst, float* __restrict__ Cc,
    float* __restrict__ ST, const float* __restrict__ A_m,
    const float* __restrict__ A_r, const short* __restrict__ gwm,
    const short* __restrict__ gwr, const float* __restrict__ s_a,
    const float* __restrict__ S0w) {
  const int wave = threadIdx.x >> 6;
  const int lane = threadIdx.x & 63;
  const int tok = blockIdx.x * 4 + wave;
  const float* xr = x + (size_t)tok * DD;
  short* b0t = b0 + (size_t)tok * DD;

  bf16x8 xb[4];
#pragma unroll
  for (int j = 0; j < 4; j++) {
    const int d0 = lane * 8 + j * 512;
    f32x4 a = *(const f32x4*)(xr + d0);
    f32x4 b = *(const f32x4*)(xr + d0 + 4);
    bf16x8 p;
#pragma unroll
    for (int q = 0; q < 4; q++) { p[q] = f2bf(a[q]); p[4 + q] = f2bf(b[q]); }
    xb[j] = p;
    *(bf16x8*)(b0t + d0) = p;
  }

  float o = 0.f, qq = 0.f, P0[4][5];
#pragma unroll
  for (int l = 0; l < 4; l++)
#pragma unroll
    for (int m = 0; m < 5; m++) P0[l][m] = 0.f;

#pragma unroll
  for (int j = 0; j < 4; j++) {
    const int d0 = lane * 8 + j * 512;
    bf16x8 wmv[4], wrv[4][4];
#pragma unroll
    for (int l = 0; l < 4; l++) {
      wmv[l] = *(const bf16x8*)(gwm + l * DD + d0);
#pragma unroll
      for (int p = 0; p < 4; p++)
        wrv[l][p] = *(const bf16x8*)(gwr + ((size_t)l * DD + d0 + 2 * p) * 4);
    }
#pragma unroll
    for (int q = 0; q < 8; q++) {
      const float hv = bf2f(xb[j][q]);
      o += hv; qq += hv * hv;
#pragma unroll
      for (int l = 0; l < 4; l++) {
        P0[l][0] += hv * bf2f(wmv[l][q]);
#pragma unroll
        for (int m = 0; m < 4; m++)
          P0[l][1 + m] += hv * bf2f(wrv[l][q >> 1][(q & 1) * 4 + m]);
      }
    }
  }
  o = wred(o); qq = wred(qq);
#pragma unroll
  for (int l = 0; l < 4; l++)
#pragma unroll
    for (int m = 0; m < 5; m++) P0[l][m] = wred(P0[l][m]);

  // block-0 width coefficients (all H rows = x)
  const float sa = s_a[0];
  const float mu = o * (1.f / DD);
  const float inv = rsqrtf(qq * (1.f / DD) - mu * mu + EPSF);
  const float t0 = tanhf(inv * (P0[0][0] - mu * S0w[0]));
  float tm[4];
#pragma unroll
  for (int m = 0; m < 4; m++)
    tm[m] = tanhf(inv * (P0[0][1 + m] - mu * S0w[1 + m]));
  float amSum = 0.f, arCol[4] = {0, 0, 0, 0};
#pragma unroll
  for (int n = 0; n < 4; n++) {
    amSum += A_m[n] + sa * t0;
#pragma unroll
    for (int m = 0; m < 4; m++) arCol[m] += A_r[n * 4 + m] + sa * tm[m];
  }

  if (lane == 0) {
    const float sh = amSum * o;
    const float sh2 = amSum * amSum * qq;
    const float mu2 = sh * (1.f / DD);
    const float inv2 = rsqrtf(sh2 * (1.f / DD) - mu2 * mu2 + EPSF);
    f32x2 t; t[0] = inv2; t[1] = mu2 * inv2;
    tst[tok] = t;
    float* STt = ST + (size_t)tok * STS;
    STt[0] = o;
    STt[4] = qq;  // G[0][0]
#pragma unroll
    for (int l = 0; l < 4; l++)
#pragma unroll
      for (int m = 0; m < 5; m++) STt[pofs(0, l) + m] = P0[l][m];
    float* Ct = Cc + (size_t)tok * 16;
#pragma unroll
    for (int n = 0; n < 4; n++) Ct[n * 4] = arCol[n];
  }

  short* hw = hout + (size_t)tok * DD;
#pragma unroll
  for (int j = 0; j < 4; j++) {
    const int d0 = lane * 8 + j * 512;
    bf16x8 ho;
#pragma unroll
    for (int q = 0; q < 8; q++) ho[q] = f2bf(amSum * bf2f(xb[j][q]));
    *(bf16x8*)(hw + d0) = ho;
  }
}

// ---------------- block GEMM: h2 = LN-folded(h @ Wt') -----------------------
// Counted-vmcnt pipeline: STAGE(kt+1) issued first, vmcnt(4) waits only for
// stage(kt), raw barriers; prefetch loads stay in flight across the barrier.
__global__ __launch_bounds__(512) void gemm_kernel(
    const short* __restrict__ A, const short* __restrict__ Bt,
    const f32x2* __restrict__ tst, const float* __restrict__ E0,
    const float* __restrict__ E1, short* __restrict__ C) {
  __shared__ short lA[2][128 * 64];
  __shared__ short lB[2][128 * 64];
  const int tid = threadIdx.x;
  const int lane = tid & 63;
  const int wave = tid >> 6;
  const int bid = blockIdx.x;
  const int wg = (bid & 7) * 64 + (bid >> 3);
  const int m0 = (wg & 31) * 128, n0 = (wg >> 5) * 128;
  const int wm = wave >> 2;
  const int wn = wave & 3;

  f32x4 acc[4][2] = {};

#define STAGE(buf, kt)                                                        \
  {                                                                           \
    const int k0 = (kt) * 64;                                                 \
    _Pragma("unroll") for (int c = 0; c < 2; c++) {                           \
      const int idx = c * 512 + tid;                                          \
      const int row = idx >> 3;                                               \
      const int colsw = (((idx & 7) ^ (row & 7)) * 8);                        \
      ld16(A + (size_t)(m0 + row) * DD + k0 + colsw,                          \
           (char*)&lA[buf][0] + idx * 16);                                    \
      ld16(Bt + (size_t)(n0 + row) * DD + k0 + colsw,                         \
           (char*)&lB[buf][0] + idx * 16);                                    \
    }                                                                         \
  }

#define COMPUTE(cur)                                                          \
  {                                                                           \
    const char* bufA = (const char*)&lA[cur][0];                              \
    const char* bufB = (const char*)&lB[cur][0];                              \
    _Pragma("unroll") for (int kk = 0; kk < 2; ++kk) {                        \
      const int gsw = (kk * 64 + (lane >> 4) * 16) ^ ((lane & 7) << 4);       \
      bf16x8 af[4], bfr[2];                                                   \
      _Pragma("unroll") for (int m = 0; m < 4; m++) {                         \
        const int r = wm * 64 + m * 16 + (lane & 15);                         \
        af[m] = *(const bf16x8*)(bufA + r * 128 + gsw);                       \
      }                                                                       \
      _Pragma("unroll") for (int n = 0; n < 2; n++) {                         \
        const int r = wn * 32 + n * 16 + (lane & 15);                         \
        bfr[n] = *(const bf16x8*)(bufB + r * 128 + gsw);                      \
      }                                                                       \
      __builtin_amdgcn_s_setprio(1);                                          \
      _Pragma("unroll") for (int m = 0; m < 4; m++)                           \
        _Pragma("unroll") for (int n = 0; n < 2; n++)                         \
          acc[m][n] = __builtin_amdgcn_mfma_f32_16x16x32_bf16(                \
              af[m], bfr[n], acc[m][n], 0, 0, 0);                             \
      __builtin_amdgcn_s_setprio(0);                                          \
    }                                                                         \
  }

  STAGE(0, 0);
  for (int kt = 0; kt < 31; ++kt) {
    const int cur = kt & 1;
    STAGE(cur ^ 1, kt + 1);                       // 4 loads -> 8 outstanding
    asm volatile("s_waitcnt vmcnt(4)" ::: "memory");  // stage(kt) landed
    asm volatile("s_barrier" ::: "memory");           // all waves agree
    COMPUTE(cur);
    asm volatile("s_barrier" ::: "memory");           // reads of buf cur done
  }
  asm volatile("s_waitcnt vmcnt(0)" ::: "memory");
  asm volatile("s_barrier" ::: "memory");
  COMPUTE(1);
#undef STAGE
#undef COMPUTE

  float e0c[2], e1c[2];
  int cols[2];
#pragma unroll
  for (int n = 0; n < 2; n++) {
    cols[n] = n0 + wn * 32 + n * 16 + (lane & 15);
    e0c[n] = E0[cols[n]];
    e1c[n] = E1[cols[n]];
  }
#pragma unroll
  for (int m = 0; m < 4; m++) {
    const int rbase = m0 + wm * 64 + m * 16 + ((lane >> 4) << 2);
#pragma unroll
    for (int j = 0; j < 4; j++) {
      const int row = rbase + j;
      const f32x2 iv = tst[row];
#pragma unroll
      for (int n = 0; n < 2; n++)
        C[(size_t)row * DD + cols[n]] =
            f2bf(iv[0] * acc[m][n][j] - iv[1] * e1c[n] + e0c[n]);
    }
  }
}

// ---------------- fused depth(I) + width(I+1) in basis form (1 wave/token) --
template <int I>
__global__ __launch_bounds__(256) void fused_dw(
    const short* __restrict__ h2s, const short* __restrict__ b0,
    short* __restrict__ hout, f32x2* __restrict__ tst, float* __restrict__ Cc,
    float* __restrict__ ST, const float* __restrict__ Bp,
    const float* __restrict__ s_b, const float* __restrict__ A_m,
    const float* __restrict__ A_r, const float* __restrict__ s_a,
    const float* __restrict__ S0w, const float* __restrict__ T0d,
    const short* __restrict__ gwm, const short* __restrict__ gwr,
    const short* __restrict__ gwb) {
  constexpr int NB = I + 1;   // width block index
  constexpr int NP = 3 - I;   // # of gw tables to dot (l = NB..3)
  const int wave = threadIdx.x >> 6;
  const int lane = threadIdx.x & 63;
  const int tok = blockIdx.x * 4 + wave;

  const short* vt = h2s + ((size_t)I * NTOK + tok) * DD;
  const short* bases[I + 1];
  bases[0] = b0 + (size_t)tok * DD;
#pragma unroll
  for (int k = 1; k <= I; k++)
    bases[k] = h2s + ((size_t)(k - 1) * NTOK + tok) * DD;

  bf16x8 h2r[4];
#pragma unroll
  for (int j = 0; j < 4; j++)
    h2r[j] = *(const bf16x8*)(vt + lane * 8 + j * 512);

  // ---- phase 1: dots on v = h2^I ----
  float o = 0.f;
  float Gr[I + 2] = {};   // Gr[k]=v.b_k (k<=I), Gr[I+1]=v.v
  float Tb[4] = {0, 0, 0, 0};
  float Pn[NP][5];
#pragma unroll
  for (int li = 0; li < NP; li++)
#pragma unroll
    for (int m = 0; m < 5; m++) Pn[li][m] = 0.f;

#pragma unroll
  for (int j = 0; j < 4; j++) {
    const int d0 = lane * 8 + j * 512;
    bf16x8 bsv[I + 1];
#pragma unroll
    for (int k = 0; k <= I; k++) bsv[k] = *(const bf16x8*)(bases[k] + d0);
    bf16x8 wbv[4];
#pragma unroll
    for (int p = 0; p < 4; p++)
      wbv[p] = *(const bf16x8*)(gwb + ((size_t)I * DD + d0 + 2 * p) * 4);
    bf16x8 wmv[NP], wrv[NP][4];
#pragma unroll
    for (int li = 0; li < NP; li++) {
      const int l = NB + li;
      wmv[li] = *(const bf16x8*)(gwm + l * DD + d0);
#pragma unroll
      for (int p = 0; p < 4; p++)
        wrv[li][p] = *(const bf16x8*)(gwr + ((size_t)l * DD + d0 + 2 * p) * 4);
    }
#pragma unroll
    for (int q = 0; q < 8; q++) {
      const float hv = bf2f(h2r[j][q]);
      o += hv;
      Gr[I + 1] += hv * hv;
#pragma unroll
      for (int k = 0; k <= I; k++) Gr[k] += hv * bf2f(bsv[k][q]);
#pragma unroll
      for (int n = 0; n < 4; n++)
        Tb[n] += hv * bf2f(wbv[q >> 1][(q & 1) * 4 + n]);
#pragma unroll
      for (int li = 0; li < NP; li++) {
        Pn[li][0] += hv * bf2f(wmv[li][q]);
#pragma unroll
        for (int m = 0; m < 4; m++)
          Pn[li][1 + m] += hv * bf2f(wrv[li][q >> 1][(q & 1) * 4 + m]);
      }
    }
  }
  o = wred(o);
#pragma unroll
  for (int k = 0; k <= I + 1; k++) Gr[k] = wred(Gr[k]);
#pragma unroll
  for (int n = 0; n < 4; n++) Tb[n] = wred(Tb[n]);
#pragma unroll
  for (int li = 0; li < NP; li++)
#pragma unroll
    for (int m = 0; m < 5; m++) Pn[li][m] = wred(Pn[li][m]);

  // ---- phase 2: coefficient algebra (wave-uniform) ----
  float* STt = ST + (size_t)tok * STS;
  float* Ct = Cc + (size_t)tok * 16;
  float ofull[I + 2], Gf[I + 2][I + 2], Pf[I + 2][5], Cp[4][I + 2];
#pragma unroll
  for (int k = 0; k <= I; k++) ofull[k] = STt[k];
  ofull[I + 1] = o;
#pragma unroll
  for (int k = 0; k <= I; k++)
#pragma unroll
    for (int j2 = 0; j2 <= I; j2++) Gf[k][j2] = STt[4 + k * 4 + j2];
#pragma unroll
  for (int k = 0; k <= I; k++) { Gf[k][I + 1] = Gr[k]; Gf[I + 1][k] = Gr[k]; }
  Gf[I + 1][I + 1] = Gr[I + 1];
#pragma unroll
  for (int k = 0; k <= I; k++)
#pragma unroll
    for (int m = 0; m < 5; m++) Pf[k][m] = STt[pofs(k, NB) + m];
#pragma unroll
  for (int m = 0; m < 5; m++) Pf[I + 1][m] = Pn[0][m];
#pragma unroll
  for (int n = 0; n < 4; n++)
#pragma unroll
    for (int k = 0; k <= I; k++) Cp[n][k] = Ct[n * 4 + k];

  // depth coefficients Bv (block I)
  {
    const float mu2 = o * (1.f / DD);
    const float inv2 = rsqrtf(Gr[I + 1] * (1.f / DD) - mu2 * mu2 + EPSF);
    const float sb = s_b[I];
#pragma unroll
    for (int n = 0; n < 4; n++)
      Cp[n][I + 1] = Bp[I * 4 + n] +
                     sb * tanhf(inv2 * (Tb[n] - mu2 * T0d[I * 4 + n]));
  }

  // width coefficients Am/Ar (block NB) from Gram-expanded stats
  const float sa = s_a[NB];
  float Am[4], Ar[4][4];
#pragma unroll
  for (int n = 0; n < 4; n++) {
    float sH = 0.f, sH2 = 0.f;
#pragma unroll
    for (int k = 0; k <= I + 1; k++) {
      sH += Cp[n][k] * ofull[k];
#pragma unroll
      for (int j2 = 0; j2 <= I + 1; j2++)
        sH2 += Cp[n][k] * Cp[n][j2] * Gf[k][j2];
    }
    const float mu = sH * (1.f / DD);
    const float inv = rsqrtf(sH2 * (1.f / DD) - mu * mu + EPSF);
    float S1[5];
#pragma unroll
    for (int m = 0; m < 5; m++) {
      S1[m] = 0.f;
#pragma unroll
      for (int k = 0; k <= I + 1; k++) S1[m] += Cp[n][k] * Pf[k][m];
    }
    Am[n] = A_m[NB * 4 + n] +
            sa * tanhf(inv * (S1[0] - mu * S0w[NB * 5 + 0]));
#pragma unroll
    for (int m = 0; m < 4; m++)
      Ar[n][m] = A_r[NB * 16 + n * 4 + m] +
                 sa * tanhf(inv * (S1[1 + m] - mu * S0w[NB * 5 + 1 + m]));
  }

  // new coefficient matrix and hnorm combo coefficients
  float Cn[4][I + 2], hc[I + 2];
#pragma unroll
  for (int k = 0; k <= I + 1; k++) {
    hc[k] = 0.f;
#pragma unroll
    for (int n = 0; n < 4; n++) hc[k] += Am[n] * Cp[n][k];
  }
#pragma unroll
  for (int mr = 0; mr < 4; mr++)
#pragma unroll
    for (int k = 0; k <= I + 1; k++) {
      float acc = 0.f;
#pragma unroll
      for (int n = 0; n < 4; n++) acc += Ar[n][mr] * Cp[n][k];
      Cn[mr][k] = acc;
    }

  if (lane == 0) {
    float sh = 0.f, sh2 = 0.f;
#pragma unroll
    for (int k = 0; k <= I + 1; k++) {
      sh += hc[k] * ofull[k];
#pragma unroll
      for (int j2 = 0; j2 <= I + 1; j2++) sh2 += hc[k] * hc[j2] * Gf[k][j2];
    }
    const float mu = sh * (1.f / DD);
    const float inv = rsqrtf(sh2 * (1.f / DD) - mu * mu + EPSF);
    f32x2 t; t[0] = inv; t[1] = mu * inv;
    tst[tok] = t;
    STt[I + 1] = o;
#pragma unroll
    for (int k = 0; k <= I + 1; k++) {
      STt[4 + (I + 1) * 4 + k] = Gf[I + 1][k];
      STt[4 + k * 4 + (I + 1)] = Gf[k][I + 1];
    }
#pragma unroll
    for (int li = 1; li < NP; li++)
#pragma unroll
      for (int m = 0; m < 5; m++) STt[pofs(I + 1, NB + li) + m] = Pn[li][m];
#pragma unroll
    for (int n = 0; n < 4; n++)
#pragma unroll
      for (int k = 0; k <= I + 1; k++) Ct[n * 4 + k] = Cn[n][k];
  }

  // ---- phase 3: hnorm = sum_k hc[k] * b_k ----
  short* hw = hout + (size_t)tok * DD;
#pragma unroll
  for (int j = 0; j < 4; j++) {
    const int d0 = lane * 8 + j * 512;
    bf16x8 bsv[I + 1];
#pragma unroll
    for (int k = 0; k <= I; k++) bsv[k] = *(const bf16x8*)(bases[k] + d0);
    bf16x8 ho;
#pragma unroll
    for (int q = 0; q < 8; q++) {
      float a = hc[I + 1] * bf2f(h2r[j][q]);
#pragma unroll
      for (int k = 0; k <= I; k++) a += hc[k] * bf2f(bsv[k][q]);
      ho[q] = f2bf(a);
    }
    *(bf16x8*)(hw + d0) = ho;
  }
}

// ---------------- final depth (block 3) + output combo ----------------------
__global__ __launch_bounds__(256) void depth_last(
    const short* __restrict__ h2s, const short* __restrict__ b0,
    float* __restrict__ out, const float* __restrict__ Cc,
    const float* __restrict__ Bp, const float* __restrict__ s_b,
    const float* __restrict__ T0d, const short* __restrict__ gwb) {
  const int wave = threadIdx.x >> 6;
  const int lane = threadIdx.x & 63;
  const int tok = blockIdx.x * 4 + wave;
  const short* vt = h2s + ((size_t)3 * NTOK + tok) * DD;

  bf16x8 h2r[4];
  float s1 = 0.f, s2 = 0.f, Tb[4] = {0, 0, 0, 0};
#pragma unroll
  for (int j = 0; j < 4; j++) {
    const int d0 = lane * 8 + j * 512;
    h2r[j] = *(const bf16x8*)(vt + d0);
    bf16x8 wbv[4];
#pragma unroll
    for (int p = 0; p < 4; p++)
      wbv[p] = *(const bf16x8*)(gwb + ((size_t)3 * DD + d0 + 2 * p) * 4);
#pragma unroll
    for (int q = 0; q < 8; q++) {
      const float hv = bf2f(h2r[j][q]);
      s1 += hv; s2 += hv * hv;
#pragma unroll
      for (int n = 0; n < 4; n++)
        Tb[n] += hv * bf2f(wbv[q >> 1][(q & 1) * 4 + n]);
    }
  }
  s1 = wred(s1); s2 = wred(s2);
#pragma unroll
  for (int n = 0; n < 4; n++) Tb[n] = wred(Tb[n]);

  const float mu = s1 * (1.f / DD);
  const float inv = rsqrtf(s2 * (1.f / DD) - mu * mu + EPSF);
  const float sb = s_b[3];
  float bsum = 0.f;
#pragma unroll
  for (int n = 0; n < 4; n++)
    bsum += Bp[12 + n] + sb * tanhf(inv * (Tb[n] - mu * T0d[12 + n]));

  const float* Ct = Cc + (size_t)tok * 16;
  float e[4];
#pragma unroll
  for (int k = 0; k < 4; k++) {
    e[k] = 0.f;
#pragma unroll
    for (int n = 0; n < 4; n++) e[k] += Ct[n * 4 + k];
  }

  const short* bases[4];
  bases[0] = b0 + (size_t)tok * DD;
#pragma unroll
  for (int k = 1; k < 4; k++)
    bases[k] = h2s + ((size_t)(k - 1) * NTOK + tok) * DD;

  float* orow = out + (size_t)tok * DD;
#pragma unroll
  for (int j = 0; j < 4; j++) {
    const int d0 = lane * 8 + j * 512;
    bf16x8 bsv[4];
#pragma unroll
    for (int k = 0; k < 4; k++) bsv[k] = *(const bf16x8*)(bases[k] + d0);
    f32x4 o0, o1;
#pragma unroll
    for (int q = 0; q < 8; q++) {
      float s = bsum * bf2f(h2r[j][q]);
#pragma unroll
      for (int k = 0; k < 4; k++) s += e[k] * bf2f(bsv[k][q]);
      if (q < 4) o0[q] = s; else o1[q - 4] = s;
    }
    *(f32x4*)(orow + d0) = o0;
    *(f32x4*)(orow + d0 + 4) = o1;
  }
}

extern "C" void kernel_launch(void* const* d_in, const int* in_sizes, int n_in,
                              void* d_out, int out_size, void* d_ws,
                              size_t ws_size, hipStream_t stream) {
  const float* x = (const float*)d_in[0];
  const float* A_m = (const float*)d_in[1];
  const float* A_r = (const float*)d_in[2];
  const float* Bp = (const float*)d_in[3];
  const float* W_m = (const float*)d_in[4];
  const float* W_r = (const float*)d_in[5];
  const float* W_b = (const float*)d_in[6];
  const float* s_a = (const float*)d_in[7];
  const float* s_b = (const float*)d_in[8];
  const float* dyn_gamma = (const float*)d_in[9];
  const float* norm_gamma = (const float*)d_in[10];
  const float* norm_beta = (const float*)d_in[11];
  const float* Wblk = (const float*)d_in[12];
  const float* bblk = (const float*)d_in[13];
  float* out = (float*)d_out;

  char* ws = (char*)d_ws;
  short* b0 = (short*)(ws);                    // 16 MiB: bf16 copy of x
  short* h2s = (short*)(ws + 16777216);        // 4 slots x 16 MiB
  short* hnorm = (short*)(ws + 83886080);      // 16 MiB
  char* aux = ws + 100663296;
  short* gwm = (short*)(aux);                  // 16 KiB
  short* gwr = (short*)(aux + 16384);          // 64 KiB
  short* gwb = (short*)(aux + 81920);          // 64 KiB
  float* rb = (float*)(aux + 147456);          // 32 KiB
  float* S0w = (float*)(aux + 180224);
  float* T0d = (float*)(aux + 181248);
  f32x2* tst = (f32x2*)(aux + 182272);         // 32 KiB
  float* E0 = (float*)(aux + 215040);          // 32 KiB
  float* E1 = (float*)(aux + 247808);          // 32 KiB
  float* Cc = (float*)(aux + 280576);          // 256 KiB: C[tok][4][4]
  float* ST = (float*)(aux + 542720);          // 1.25 MiB: stats[tok][80]
  short* Wt = (short*)d_out;  // recomputed every call, overwritten at end

  dim3 tb(256);
  prep_pack<<<32, tb, 0, stream>>>(W_m, W_r, W_b, dyn_gamma, norm_gamma,
                                   norm_beta, gwm, gwr, gwb, rb);
  prep_sums<<<4, dim3(64), 0, stream>>>(W_m, W_r, W_b, dyn_gamma, S0w, T0d);
  transpose_wblk<<<dim3(32, 32, 4), tb, 0, stream>>>(Wblk, norm_gamma, Wt);
  row_sums<<<dim3(512, 4), tb, 0, stream>>>(Wt, rb, bblk, E0, E1);
  width0_kernel<<<1024, tb, 0, stream>>>(x, b0, hnorm, tst, Cc, ST, A_m, A_r,
                                         gwm, gwr, s_a, S0w);
  for (int i = 0; i < LL; i++) {
    gemm_kernel<<<512, dim3(512), 0, stream>>>(
        hnorm, Wt + (size_t)i * DD * DD, tst, E0 + i * DD, E1 + i * DD,
        h2s + (size_t)i * NTOK * DD);
    if (i == 0)
      fused_dw<0><<<1024, tb, 0, stream>>>(h2s, b0, hnorm, tst, Cc, ST, Bp,
                                           s_b, A_m, A_r, s_a, S0w, T0d, gwm,
                                           gwr, gwb);
    else if (i == 1)
      fused_dw<1><<<1024, tb, 0, stream>>>(h2s, b0, hnorm, tst, Cc, ST, Bp,
                                           s_b, A_m, A_r, s_a, S0w, T0d, gwm,
                                           gwr, gwb);
    else if (i == 2)
      fused_dw<2><<<1024, tb, 0, stream>>>(h2s, b0, hnorm, tst, Cc, ST, Bp,
                                           s_b, A_m, A_r, s_a, S0w, T0d, gwm,
                                           gwr, gwb);
    else
      depth_last<<<1024, tb, 0, stream>>>(h2s, b0, out, Cc, Bp, s_b, T0d, gwb);
  }
}